// Round 1
// baseline (1848.463 us; speedup 1.0000x reference)
//
#include <hip/hip_runtime.h>
#include <math.h>

#define BB 2
#define SS 2048
#define DD 1024
#define HH 16
#define TOPK 512
#define ROWS (BB*SS)

__device__ __forceinline__ unsigned fkey(float f) {
  unsigned u = __float_as_uint(f);
  if ((u << 1) == 0u) u = 0u;             // canonicalize -0.0 -> +0.0 (ref compares floats)
  return (u & 0x80000000u) ? ~u : (u | 0x80000000u);
}

__global__ void rope_tab_k(float* __restrict__ ct, float* __restrict__ st) {
  int idx = blockIdx.x * blockDim.x + threadIdx.x;
  if (idx >= SS * 32) return;
  int s = idx >> 5, j = idx & 31;
  float theta = 1.0f / powf(10000.0f, (float)(2 * j) / 64.0f);
  float ang = (float)s * theta;
  float sv, cv;
  sincosf(ang, &sv, &cv);
  ct[idx] = cv;
  st[idx] = sv;
}

// fp32 GEMM, 128x128 tile, BK=16, 256 threads, 8x8 per thread.
// EPI==0: plain store to C (N-bounds-checked if BND). EPI==1: qkv RoPE epilogue -> Qr/Kr/Vr.
template<int EPI, bool BND>
__global__ __launch_bounds__(256) void gemm128(
    const float* __restrict__ A, const float* __restrict__ Bw, float* __restrict__ C,
    int M, int N, int K,
    const float* __restrict__ ct, const float* __restrict__ st,
    float* __restrict__ Qr, float* __restrict__ Kr, float* __restrict__ Vr)
{
  __shared__ float As[16][132];
  __shared__ float Bs[16][132];
  int n0 = blockIdx.x * 128, m0 = blockIdx.y * 128;
  int tid = threadIdx.x;
  int tm = (tid >> 4) << 3;
  int tn = (tid & 15) << 3;
  float acc[8][8];
#pragma unroll
  for (int i = 0; i < 8; ++i)
#pragma unroll
    for (int j = 0; j < 8; ++j) acc[i][j] = 0.0f;

  for (int k0 = 0; k0 < K; k0 += 16) {
#pragma unroll
    for (int q = 0; q < 2; ++q) {
      int lin = tid * 4 + q * 1024;
      int row = lin >> 4, kk = lin & 15;
      float4 av = *(const float4*)(A + (size_t)(m0 + row) * K + k0 + kk);
      As[kk + 0][row] = av.x; As[kk + 1][row] = av.y;
      As[kk + 2][row] = av.z; As[kk + 3][row] = av.w;
      int bk = lin >> 7, bc = lin & 127;
      float4 bv;
      if (!BND || (n0 + bc) < N)
        bv = *(const float4*)(Bw + (size_t)(k0 + bk) * N + n0 + bc);
      else
        bv = make_float4(0.f, 0.f, 0.f, 0.f);
      *(float4*)&Bs[bk][bc] = bv;
    }
    __syncthreads();
#pragma unroll
    for (int k = 0; k < 16; ++k) {
      float a[8], bb[8];
      *(float4*)&a[0]  = *(const float4*)&As[k][tm];
      *(float4*)&a[4]  = *(const float4*)&As[k][tm + 4];
      *(float4*)&bb[0] = *(const float4*)&Bs[k][tn];
      *(float4*)&bb[4] = *(const float4*)&Bs[k][tn + 4];
#pragma unroll
      for (int i = 0; i < 8; ++i)
#pragma unroll
        for (int j = 0; j < 8; ++j)
          acc[i][j] = fmaf(a[i], bb[j], acc[i][j]);
    }
    __syncthreads();
  }

  if (EPI == 0) {
#pragma unroll
    for (int i = 0; i < 8; ++i) {
      size_t m = (size_t)(m0 + tm + i);
      float* crow = C + m * (size_t)N;
#pragma unroll
      for (int jc = 0; jc < 2; ++jc) {
        int cb = n0 + tn + jc * 4;
        if (!BND || cb < N) {
          *(float4*)(crow + cb) = make_float4(acc[i][jc*4], acc[i][jc*4+1],
                                              acc[i][jc*4+2], acc[i][jc*4+3]);
        }
      }
    }
  } else {
    int nb = n0 + tn;
    int sec = nb >> 10;          // 0=q 1=k 2=v
    int cin = nb & 1023;         // h*64+d
    int jbase = (cin & 63) >> 1; // first rotary pair index of this 8-col strip
#pragma unroll
    for (int i = 0; i < 8; ++i) {
      int m = m0 + tm + i;
      int tt = m & (SS - 1);
      size_t orow = (size_t)m * 1024 + cin;
      if (sec == 2) {
        *(float4*)(Vr + orow)     = make_float4(acc[i][0], acc[i][1], acc[i][2], acc[i][3]);
        *(float4*)(Vr + orow + 4) = make_float4(acc[i][4], acc[i][5], acc[i][6], acc[i][7]);
      } else {
        float o[8];
#pragma unroll
        for (int c = 0; c < 4; ++c) {
          float cv = ct[tt * 32 + jbase + c];
          float sv = st[tt * 32 + jbase + c];
          float x1 = acc[i][2 * c], x2 = acc[i][2 * c + 1];
          o[2 * c]     = x1 * cv - x2 * sv;
          o[2 * c + 1] = x2 * cv + x1 * sv;
        }
        float* dst = (sec == 0) ? Qr : Kr;
        *(float4*)(dst + orow)     = make_float4(o[0], o[1], o[2], o[3]);
        *(float4*)(dst + orow + 4) = make_float4(o[4], o[5], o[6], o[7]);
      }
    }
  }
}

// Per (b,t): compute indexer scores for s<=t, exact top-512 (stable, lowest-index ties).
__global__ __launch_bounds__(256) void idx_topk_k(
    const float* __restrict__ qi, const float* __restrict__ ki,
    const float* __restrict__ wI, int* __restrict__ sel)
{
  int t = blockIdx.x, b = blockIdx.y;
  int tid = threadIdx.x;
  int* srow = sel + ((size_t)b * SS + t) * TOPK;
  if (t < TOPK) {  // ref's -1e9 ties => selection is exactly [0..511]
    for (int i = tid; i < TOPK; i += 256) srow[i] = i;
    return;
  }
  __shared__ float sc[SS];
  __shared__ unsigned hist[256];
  __shared__ unsigned hs[256];
  __shared__ unsigned s_bsel, s_above, s_cnt;

  const float4* qrow = (const float4*)(qi + ((size_t)b * SS + t) * 256);
  const float* wrow = wI + ((size_t)b * SS + t) * 4;
  float w0 = wrow[0], w1 = wrow[1], w2 = wrow[2], w3 = wrow[3];

  for (int s = tid; s <= t; s += 256) {
    const float4* kp = (const float4*)(ki + ((size_t)b * SS + s) * 64);
    float a0 = 0.f, a1 = 0.f, a2 = 0.f, a3 = 0.f;
#pragma unroll
    for (int d4 = 0; d4 < 16; ++d4) {
      float4 kv = kp[d4];
      float4 q0 = qrow[d4];
      float4 q1 = qrow[16 + d4];
      float4 q2 = qrow[32 + d4];
      float4 q3 = qrow[48 + d4];
      a0 += q0.x * kv.x + q0.y * kv.y + q0.z * kv.z + q0.w * kv.w;
      a1 += q1.x * kv.x + q1.y * kv.y + q1.z * kv.z + q1.w * kv.w;
      a2 += q2.x * kv.x + q2.y * kv.y + q2.z * kv.z + q2.w * kv.w;
      a3 += q3.x * kv.x + q3.y * kv.y + q3.z * kv.z + q3.w * kv.w;
    }
    float v = fmaxf(a0, 0.f) * w0 + fmaxf(a1, 0.f) * w1 +
              fmaxf(a2, 0.f) * w2 + fmaxf(a3, 0.f) * w3;
    sc[s] = v;
  }
  __syncthreads();

  unsigned krem = TOPK;
  unsigned prefix = 0;
#pragma unroll 1
  for (int p = 0; p < 4; ++p) {
    int shift = 24 - 8 * p;
    unsigned maskAbove = (p == 0) ? 0u : (0xFFFFFFFFu << (shift + 8));
    hist[tid] = 0u;
    __syncthreads();
    for (int s = tid; s <= t; s += 256) {
      unsigned key = fkey(sc[s]);
      if ((key & maskAbove) == prefix)
        atomicAdd(&hist[(key >> shift) & 255], 1u);
    }
    __syncthreads();
    hs[tid] = hist[tid];
    __syncthreads();
#pragma unroll 1
    for (int off = 1; off < 256; off <<= 1) {   // inclusive suffix-sum
      unsigned v = (tid + off < 256) ? hs[tid + off] : 0u;
      __syncthreads();
      hs[tid] += v;
      __syncthreads();
    }
    unsigned mine = hs[tid];
    unsigned nxt = (tid < 255) ? hs[tid + 1] : 0u;
    if (mine >= krem && nxt < krem) { s_bsel = (unsigned)tid; s_above = nxt; }
    __syncthreads();
    prefix |= (s_bsel << shift);
    krem -= s_above;
    __syncthreads();
  }

  unsigned Tkey = prefix;
  unsigned kfin = krem;             // number of ==T to take (lowest indices)
  if (tid == 0) s_cnt = 0u;
  __syncthreads();
  for (int s = tid; s <= t; s += 256) {
    if (fkey(sc[s]) > Tkey) {
      unsigned pp = atomicAdd(&s_cnt, 1u);
      srow[pp] = s;
    }
  }
  __syncthreads();
  unsigned cgt = s_cnt;             // == TOPK - kfin
  if (tid < 64) {
    unsigned taken = 0;
    for (int s0 = 0; s0 <= t && taken < kfin; s0 += 64) {
      int s = s0 + tid;
      bool pred = (s <= t) && (fkey(sc[s]) == Tkey);
      unsigned long long mba = __ballot(pred);
      unsigned pre = (unsigned)__popcll(mba & ((1ull << tid) - 1ull));
      if (pred && (taken + pre) < kfin) srow[cgt + taken + pre] = s;
      taken += (unsigned)__popcll(mba);
    }
  }
}

// Gather attention: one workgroup per (b,t). K/V layout (b,s,h*64) -> one 4KB row
// per selected key reused across all 16 heads.
__global__ __launch_bounds__(256) void attn_k(
    const float* __restrict__ Qr, const float* __restrict__ Kr, const float* __restrict__ Vr,
    const int* __restrict__ sel, float* __restrict__ attnO)
{
  int t = blockIdx.x, b = blockIdx.y;
  int tid = threadIdx.x;
  int lane = tid & 63;
  int wv = tid >> 6;
  __shared__ float P[TOPK][17];
  __shared__ int sidx[TOPK];
  __shared__ float denomS[16];

  if (t < TOPK) {
    for (int i = tid; i < TOPK; i += 256) sidx[i] = i;
  } else {
    const int* srow = sel + ((size_t)b * SS + t) * TOPK;
    for (int i = tid; i < TOPK; i += 256) sidx[i] = srow[i];
  }
  const float* qrow = Qr + ((size_t)b * SS + t) * 1024 + lane * 16;
  float4 qf0 = *(const float4*)(qrow);
  float4 qf1 = *(const float4*)(qrow + 4);
  float4 qf2 = *(const float4*)(qrow + 8);
  float4 qf3 = *(const float4*)(qrow + 12);
  __syncthreads();

  int h4 = lane >> 2;
  for (int i = wv * 128; i < wv * 128 + 128; ++i) {
    int s = sidx[i];
    const float4* kp = (const float4*)(Kr + ((size_t)b * SS + s) * 1024 + lane * 16);
    float4 k0 = kp[0], k1 = kp[1], k2 = kp[2], k3 = kp[3];
    float d = qf0.x * k0.x + qf0.y * k0.y + qf0.z * k0.z + qf0.w * k0.w;
    d += qf1.x * k1.x + qf1.y * k1.y + qf1.z * k1.z + qf1.w * k1.w;
    d += qf2.x * k2.x + qf2.y * k2.y + qf2.z * k2.z + qf2.w * k2.w;
    d += qf3.x * k3.x + qf3.y * k3.y + qf3.z * k3.z + qf3.w * k3.w;
    d += __shfl_xor(d, 1);
    d += __shfl_xor(d, 2);
    if ((lane & 3) == 0) P[i][h4] = d * 0.125f;
  }
  __syncthreads();

  int h = tid >> 4, i0 = tid & 15;
  float mx = -3.0e38f;
  for (int i = i0; i < TOPK; i += 16) mx = fmaxf(mx, P[i][h]);
#pragma unroll
  for (int off = 1; off < 16; off <<= 1) mx = fmaxf(mx, __shfl_xor(mx, off));
  float sum = 0.f;
  for (int i = i0; i < TOPK; i += 16) {
    float e = __expf(P[i][h] - mx);
    P[i][h] = e;
    sum += e;
  }
#pragma unroll
  for (int off = 1; off < 16; off <<= 1) sum += __shfl_xor(sum, off);
  if (i0 == 0) denomS[h] = sum;
  __syncthreads();

  int dq = (tid & 15) << 2;
  float ax = 0.f, ay = 0.f, az = 0.f, aw = 0.f;
  for (int i = 0; i < TOPK; ++i) {
    int s = sidx[i];
    float pv = P[i][h];
    float4 vvv = *(const float4*)(Vr + ((size_t)b * SS + s) * 1024 + h * 64 + dq);
    ax = fmaf(pv, vvv.x, ax);
    ay = fmaf(pv, vvv.y, ay);
    az = fmaf(pv, vvv.z, az);
    aw = fmaf(pv, vvv.w, aw);
  }
  float inv = 1.0f / denomS[h];
  *(float4*)(attnO + ((size_t)b * SS + t) * 1024 + h * 64 + dq) =
      make_float4(ax * inv, ay * inv, az * inv, aw * inv);
}

extern "C" void kernel_launch(void* const* d_in, const int* in_sizes, int n_in,
                              void* d_out, int out_size, void* d_ws, size_t ws_size,
                              hipStream_t stream) {
  const float* x    = (const float*)d_in[0];
  const float* Wqkv = (const float*)d_in[1];
  const float* Wo   = (const float*)d_in[2];
  const float* Wq   = (const float*)d_in[3];
  const float* Wk   = (const float*)d_in[4];
  const float* Ww   = (const float*)d_in[5];
  float* out = (float*)d_out;

  float* fws = (float*)d_ws;
  size_t o = 0;
  float* Qr    = fws + o; o += (size_t)ROWS * 1024;
  float* Kr    = fws + o; o += (size_t)ROWS * 1024;
  float* Vr    = fws + o; o += (size_t)ROWS * 1024;
  float* attnO = fws + o; o += (size_t)ROWS * 1024;
  float* qi    = fws + o; o += (size_t)ROWS * 256;
  float* kii   = fws + o; o += (size_t)ROWS * 64;
  float* wI    = fws + o; o += (size_t)ROWS * 4;
  float* ct    = fws + o; o += (size_t)SS * 32;
  float* st    = fws + o; o += (size_t)SS * 32;
  int*   sel   = (int*)(fws + o); o += (size_t)ROWS * TOPK;

  rope_tab_k<<<dim3((SS * 32 + 255) / 256), dim3(256), 0, stream>>>(ct, st);

  // qkv + RoPE
  gemm128<1, false><<<dim3(3072 / 128, ROWS / 128), dim3(256), 0, stream>>>(
      x, Wqkv, nullptr, ROWS, 3072, 1024, ct, st, Qr, Kr, Vr);
  // indexer projections
  gemm128<0, true><<<dim3(2, ROWS / 128), dim3(256), 0, stream>>>(
      x, Wq, qi, ROWS, 256, 1024, nullptr, nullptr, nullptr, nullptr, nullptr);
  gemm128<0, true><<<dim3(1, ROWS / 128), dim3(256), 0, stream>>>(
      x, Wk, kii, ROWS, 64, 1024, nullptr, nullptr, nullptr, nullptr, nullptr);
  gemm128<0, true><<<dim3(1, ROWS / 128), dim3(256), 0, stream>>>(
      x, Ww, wI, ROWS, 4, 1024, nullptr, nullptr, nullptr, nullptr, nullptr);

  idx_topk_k<<<dim3(SS, BB), dim3(256), 0, stream>>>(qi, kii, wI, sel);
  attn_k<<<dim3(SS, BB), dim3(256), 0, stream>>>(Qr, Kr, Vr, sel, attnO);

  // out = attn @ Wo
  gemm128<0, false><<<dim3(1024 / 128, ROWS / 128), dim3(256), 0, stream>>>(
      attnO, Wo, out, ROWS, 1024, 1024, nullptr, nullptr, nullptr, nullptr, nullptr);
}

// Round 2
// 1434.862 us; speedup vs baseline: 1.2883x; 1.2883x over previous
//
#include <hip/hip_runtime.h>
#include <hip/hip_fp16.h>
#include <math.h>

#define BB 2
#define SS 2048
#define DD 1024
#define HH 16
#define TOPK 512
#define ROWS (BB*SS)

__device__ __forceinline__ unsigned fkey(float f) {
  unsigned u = __float_as_uint(f);
  if ((u << 1) == 0u) u = 0u;             // canonicalize -0.0 -> +0.0 (ref compares floats)
  return (u & 0x80000000u) ? ~u : (u | 0x80000000u);
}

__global__ void rope_tab_k(float* __restrict__ ct, float* __restrict__ st) {
  int idx = blockIdx.x * blockDim.x + threadIdx.x;
  if (idx >= SS * 32) return;
  int s = idx >> 5, j = idx & 31;
  float theta = 1.0f / powf(10000.0f, (float)(2 * j) / 64.0f);
  float ang = (float)s * theta;
  float sv, cv;
  sincosf(ang, &sv, &cv);
  ct[idx] = cv;
  st[idx] = sv;
}

// fp32 GEMM, 128x128 tile, BK=16, 256 threads, 8x8 per thread.
// EPI==0: plain store to C (N-bounds-checked if BND). EPI==1: qkv RoPE epilogue -> Qr(f32)/Kh(f16)/Vh(f16).
template<int EPI, bool BND>
__global__ __launch_bounds__(256) void gemm128(
    const float* __restrict__ A, const float* __restrict__ Bw, float* __restrict__ C,
    int M, int N, int K,
    const float* __restrict__ ct, const float* __restrict__ st,
    float* __restrict__ Qr, __half* __restrict__ Kh, __half* __restrict__ Vh)
{
  __shared__ float As[16][132];
  __shared__ float Bs[16][132];
  int n0 = blockIdx.x * 128, m0 = blockIdx.y * 128;
  int tid = threadIdx.x;
  int tm = (tid >> 4) << 3;
  int tn = (tid & 15) << 3;
  float acc[8][8];
#pragma unroll
  for (int i = 0; i < 8; ++i)
#pragma unroll
    for (int j = 0; j < 8; ++j) acc[i][j] = 0.0f;

  for (int k0 = 0; k0 < K; k0 += 16) {
#pragma unroll
    for (int q = 0; q < 2; ++q) {
      int lin = tid * 4 + q * 1024;
      int row = lin >> 4, kk = lin & 15;
      float4 av = *(const float4*)(A + (size_t)(m0 + row) * K + k0 + kk);
      As[kk + 0][row] = av.x; As[kk + 1][row] = av.y;
      As[kk + 2][row] = av.z; As[kk + 3][row] = av.w;
      int bk = lin >> 7, bc = lin & 127;
      float4 bv;
      if (!BND || (n0 + bc) < N)
        bv = *(const float4*)(Bw + (size_t)(k0 + bk) * N + n0 + bc);
      else
        bv = make_float4(0.f, 0.f, 0.f, 0.f);
      *(float4*)&Bs[bk][bc] = bv;
    }
    __syncthreads();
#pragma unroll
    for (int k = 0; k < 16; ++k) {
      float a[8], bb[8];
      *(float4*)&a[0]  = *(const float4*)&As[k][tm];
      *(float4*)&a[4]  = *(const float4*)&As[k][tm + 4];
      *(float4*)&bb[0] = *(const float4*)&Bs[k][tn];
      *(float4*)&bb[4] = *(const float4*)&Bs[k][tn + 4];
#pragma unroll
      for (int i = 0; i < 8; ++i)
#pragma unroll
        for (int j = 0; j < 8; ++j)
          acc[i][j] = fmaf(a[i], bb[j], acc[i][j]);
    }
    __syncthreads();
  }

  if (EPI == 0) {
#pragma unroll
    for (int i = 0; i < 8; ++i) {
      size_t m = (size_t)(m0 + tm + i);
      float* crow = C + m * (size_t)N;
#pragma unroll
      for (int jc = 0; jc < 2; ++jc) {
        int cb = n0 + tn + jc * 4;
        if (!BND || cb < N) {
          *(float4*)(crow + cb) = make_float4(acc[i][jc*4], acc[i][jc*4+1],
                                              acc[i][jc*4+2], acc[i][jc*4+3]);
        }
      }
    }
  } else {
    int nb = n0 + tn;
    int sec = nb >> 10;          // 0=q 1=k 2=v
    int cin = nb & 1023;         // h*64+d
    int jbase = (cin & 63) >> 1; // first rotary pair index of this 8-col strip
#pragma unroll
    for (int i = 0; i < 8; ++i) {
      int m = m0 + tm + i;
      int tt = m & (SS - 1);
      size_t orow = (size_t)m * 1024 + cin;
      if (sec == 2) {
        __half2 hh[4];
        hh[0] = __floats2half2_rn(acc[i][0], acc[i][1]);
        hh[1] = __floats2half2_rn(acc[i][2], acc[i][3]);
        hh[2] = __floats2half2_rn(acc[i][4], acc[i][5]);
        hh[3] = __floats2half2_rn(acc[i][6], acc[i][7]);
        *(float4*)(Vh + orow) = *(float4*)hh;
      } else {
        float o[8];
#pragma unroll
        for (int c = 0; c < 4; ++c) {
          float cv = ct[tt * 32 + jbase + c];
          float sv = st[tt * 32 + jbase + c];
          float x1 = acc[i][2 * c], x2 = acc[i][2 * c + 1];
          o[2 * c]     = x1 * cv - x2 * sv;
          o[2 * c + 1] = x2 * cv + x1 * sv;
        }
        if (sec == 0) {
          *(float4*)(Qr + orow)     = make_float4(o[0], o[1], o[2], o[3]);
          *(float4*)(Qr + orow + 4) = make_float4(o[4], o[5], o[6], o[7]);
        } else {
          __half2 hh[4];
          hh[0] = __floats2half2_rn(o[0], o[1]);
          hh[1] = __floats2half2_rn(o[2], o[3]);
          hh[2] = __floats2half2_rn(o[4], o[5]);
          hh[3] = __floats2half2_rn(o[6], o[7]);
          *(float4*)(Kh + orow) = *(float4*)hh;
        }
      }
    }
  }
}

// Per (b,t): compute indexer scores for s<=t, exact top-512 (stable, lowest-index ties).
__global__ __launch_bounds__(256) void idx_topk_k(
    const float* __restrict__ qi, const float* __restrict__ ki,
    const float* __restrict__ wI, int* __restrict__ sel)
{
  int t = blockIdx.x, b = blockIdx.y;
  int tid = threadIdx.x;
  int* srow = sel + ((size_t)b * SS + t) * TOPK;
  if (t < TOPK) {  // ref's -1e9 ties => selection is exactly [0..511]
    for (int i = tid; i < TOPK; i += 256) srow[i] = i;
    return;
  }
  __shared__ float sc[SS];
  __shared__ unsigned hist[256];
  __shared__ unsigned hs[256];
  __shared__ unsigned s_bsel, s_above, s_cnt;

  const float4* qrow = (const float4*)(qi + ((size_t)b * SS + t) * 256);
  const float* wrow = wI + ((size_t)b * SS + t) * 4;
  float w0 = wrow[0], w1 = wrow[1], w2 = wrow[2], w3 = wrow[3];

  for (int s = tid; s <= t; s += 256) {
    const float4* kp = (const float4*)(ki + ((size_t)b * SS + s) * 64);
    float a0 = 0.f, a1 = 0.f, a2 = 0.f, a3 = 0.f;
#pragma unroll
    for (int d4 = 0; d4 < 16; ++d4) {
      float4 kv = kp[d4];
      float4 q0 = qrow[d4];
      float4 q1 = qrow[16 + d4];
      float4 q2 = qrow[32 + d4];
      float4 q3 = qrow[48 + d4];
      a0 += q0.x * kv.x + q0.y * kv.y + q0.z * kv.z + q0.w * kv.w;
      a1 += q1.x * kv.x + q1.y * kv.y + q1.z * kv.z + q1.w * kv.w;
      a2 += q2.x * kv.x + q2.y * kv.y + q2.z * kv.z + q2.w * kv.w;
      a3 += q3.x * kv.x + q3.y * kv.y + q3.z * kv.z + q3.w * kv.w;
    }
    float v = fmaxf(a0, 0.f) * w0 + fmaxf(a1, 0.f) * w1 +
              fmaxf(a2, 0.f) * w2 + fmaxf(a3, 0.f) * w3;
    sc[s] = v;
  }
  __syncthreads();

  unsigned krem = TOPK;
  unsigned prefix = 0;
#pragma unroll 1
  for (int p = 0; p < 4; ++p) {
    int shift = 24 - 8 * p;
    unsigned maskAbove = (p == 0) ? 0u : (0xFFFFFFFFu << (shift + 8));
    hist[tid] = 0u;
    __syncthreads();
    for (int s = tid; s <= t; s += 256) {
      unsigned key = fkey(sc[s]);
      if ((key & maskAbove) == prefix)
        atomicAdd(&hist[(key >> shift) & 255], 1u);
    }
    __syncthreads();
    hs[tid] = hist[tid];
    __syncthreads();
#pragma unroll 1
    for (int off = 1; off < 256; off <<= 1) {   // inclusive suffix-sum
      unsigned v = (tid + off < 256) ? hs[tid + off] : 0u;
      __syncthreads();
      hs[tid] += v;
      __syncthreads();
    }
    unsigned mine = hs[tid];
    unsigned nxt = (tid < 255) ? hs[tid + 1] : 0u;
    if (mine >= krem && nxt < krem) { s_bsel = (unsigned)tid; s_above = nxt; }
    __syncthreads();
    prefix |= (s_bsel << shift);
    krem -= s_above;
    __syncthreads();
  }

  unsigned Tkey = prefix;
  unsigned kfin = krem;             // number of ==T to take (lowest indices)
  if (tid == 0) s_cnt = 0u;
  __syncthreads();
  for (int s = tid; s <= t; s += 256) {
    if (fkey(sc[s]) > Tkey) {
      unsigned pp = atomicAdd(&s_cnt, 1u);
      srow[pp] = s;
    }
  }
  __syncthreads();
  unsigned cgt = s_cnt;             // == TOPK - kfin
  if (tid < 64) {
    unsigned taken = 0;
    for (int s0 = 0; s0 <= t && taken < kfin; s0 += 64) {
      int s = s0 + tid;
      bool pred = (s <= t) && (fkey(sc[s]) == Tkey);
      unsigned long long mba = __ballot(pred);
      unsigned pre = (unsigned)__popcll(mba & ((1ull << tid) - 1ull));
      if (pred && (taken + pre) < kfin) srow[cgt + taken + pre] = s;
      taken += (unsigned)__popcll(mba);
    }
  }
}

// Gather attention: one workgroup per (b,t). K/V stored fp16 in (b,s,h*64) layout.
__global__ __launch_bounds__(256) void attn_k(
    const float* __restrict__ Qr, const __half* __restrict__ Kh, const __half* __restrict__ Vh,
    const int* __restrict__ sel, float* __restrict__ attnO)
{
  int t = blockIdx.x, b = blockIdx.y;
  int tid = threadIdx.x;
  int lane = tid & 63;
  int wv = tid >> 6;
  __shared__ float P[TOPK][17];
  __shared__ int sidx[TOPK];
  __shared__ float denomS[16];

  if (t < TOPK) {
    for (int i = tid; i < TOPK; i += 256) sidx[i] = i;
  } else {
    const int* srow = sel + ((size_t)b * SS + t) * TOPK;
    for (int i = tid; i < TOPK; i += 256) sidx[i] = srow[i];
  }
  // Q fragment: lane covers head (lane>>2), dims [(lane&3)*16, +16)
  const float* qrow = Qr + ((size_t)b * SS + t) * 1024 + lane * 16;
  float q[16];
  *(float4*)&q[0]  = *(const float4*)(qrow);
  *(float4*)&q[4]  = *(const float4*)(qrow + 4);
  *(float4*)&q[8]  = *(const float4*)(qrow + 8);
  *(float4*)&q[12] = *(const float4*)(qrow + 12);
  __syncthreads();

  int h4 = lane >> 2;
  const size_t brow = (size_t)b * SS;
  // QK^T: each wave handles 128 keys, unroll x2 for ILP
  for (int i = wv * 128; i < wv * 128 + 128; i += 2) {
    int s0 = sidx[i], s1 = sidx[i + 1];
    const __half2* kp0 = (const __half2*)(Kh + (brow + s0) * 1024 + lane * 16);
    const __half2* kp1 = (const __half2*)(Kh + (brow + s1) * 1024 + lane * 16);
    float4 ra0 = *(const float4*)(kp0);      // halfs 0..7
    float4 ra1 = *(const float4*)(kp0 + 4);  // halfs 8..15
    float4 rb0 = *(const float4*)(kp1);
    float4 rb1 = *(const float4*)(kp1 + 4);
    const __half2* ha0 = (const __half2*)&ra0;
    const __half2* ha1 = (const __half2*)&ra1;
    const __half2* hb0 = (const __half2*)&rb0;
    const __half2* hb1 = (const __half2*)&rb1;
    float d0 = 0.f, d1 = 0.f;
#pragma unroll
    for (int u = 0; u < 4; ++u) {
      float2 f = __half22float2(ha0[u]);
      d0 = fmaf(q[2*u], f.x, d0); d0 = fmaf(q[2*u+1], f.y, d0);
      float2 g = __half22float2(ha1[u]);
      d0 = fmaf(q[8+2*u], g.x, d0); d0 = fmaf(q[8+2*u+1], g.y, d0);
      float2 fb = __half22float2(hb0[u]);
      d1 = fmaf(q[2*u], fb.x, d1); d1 = fmaf(q[2*u+1], fb.y, d1);
      float2 gb = __half22float2(hb1[u]);
      d1 = fmaf(q[8+2*u], gb.x, d1); d1 = fmaf(q[8+2*u+1], gb.y, d1);
    }
    d0 += __shfl_xor(d0, 1); d0 += __shfl_xor(d0, 2);
    d1 += __shfl_xor(d1, 1); d1 += __shfl_xor(d1, 2);
    if ((lane & 3) == 0) {
      P[i][h4]     = d0 * 0.125f;
      P[i + 1][h4] = d1 * 0.125f;
    }
  }
  __syncthreads();

  int h = tid >> 4, i0 = tid & 15;
  float mx = -3.0e38f;
  for (int i = i0; i < TOPK; i += 16) mx = fmaxf(mx, P[i][h]);
#pragma unroll
  for (int off = 1; off < 16; off <<= 1) mx = fmaxf(mx, __shfl_xor(mx, off));
  float sum = 0.f;
  for (int i = i0; i < TOPK; i += 16) {
    float e = __expf(P[i][h] - mx);
    P[i][h] = e;
    sum += e;
  }
#pragma unroll
  for (int off = 1; off < 16; off <<= 1) sum += __shfl_xor(sum, off);
  if (i0 == 0) denomS[h] = sum;
  __syncthreads();

  // PV: thread (h, dq) accumulates 4 output dims; 8B fp16 loads; unroll x4
  int dq = (tid & 15) << 2;
  size_t hoff = h * 64 + dq;
  float ax = 0.f, ay = 0.f, az = 0.f, aw = 0.f;
  for (int i = 0; i < TOPK; i += 4) {
#pragma unroll
    for (int u = 0; u < 4; ++u) {
      int s = sidx[i + u];
      float pv = P[i + u][h];
      float2 rv = *(const float2*)(Vh + (brow + s) * 1024 + hoff);
      const __half2* hv = (const __half2*)&rv;
      float2 v0 = __half22float2(hv[0]);
      float2 v1 = __half22float2(hv[1]);
      ax = fmaf(pv, v0.x, ax);
      ay = fmaf(pv, v0.y, ay);
      az = fmaf(pv, v1.x, az);
      aw = fmaf(pv, v1.y, aw);
    }
  }
  float inv = 1.0f / denomS[h];
  *(float4*)(attnO + (brow + t) * 1024 + hoff) =
      make_float4(ax * inv, ay * inv, az * inv, aw * inv);
}

extern "C" void kernel_launch(void* const* d_in, const int* in_sizes, int n_in,
                              void* d_out, int out_size, void* d_ws, size_t ws_size,
                              hipStream_t stream) {
  const float* x    = (const float*)d_in[0];
  const float* Wqkv = (const float*)d_in[1];
  const float* Wo   = (const float*)d_in[2];
  const float* Wq   = (const float*)d_in[3];
  const float* Wk   = (const float*)d_in[4];
  const float* Ww   = (const float*)d_in[5];
  float* out = (float*)d_out;

  float* fws = (float*)d_ws;
  size_t o = 0;
  float* Qr    = fws + o; o += (size_t)ROWS * 1024;
  float* attnO = fws + o; o += (size_t)ROWS * 1024;
  __half* Kh   = (__half*)(fws + o); o += (size_t)ROWS * 512;
  __half* Vh   = (__half*)(fws + o); o += (size_t)ROWS * 512;
  float* qi    = fws + o; o += (size_t)ROWS * 256;
  float* kii   = fws + o; o += (size_t)ROWS * 64;
  float* wI    = fws + o; o += (size_t)ROWS * 4;
  float* ct    = fws + o; o += (size_t)SS * 32;
  float* st    = fws + o; o += (size_t)SS * 32;
  int*   sel   = (int*)(fws + o); o += (size_t)ROWS * TOPK;

  rope_tab_k<<<dim3((SS * 32 + 255) / 256), dim3(256), 0, stream>>>(ct, st);

  // qkv + RoPE (Q fp32, K/V fp16)
  gemm128<1, false><<<dim3(3072 / 128, ROWS / 128), dim3(256), 0, stream>>>(
      x, Wqkv, nullptr, ROWS, 3072, 1024, ct, st, Qr, Kh, Vh);
  // indexer projections
  gemm128<0, true><<<dim3(2, ROWS / 128), dim3(256), 0, stream>>>(
      x, Wq, qi, ROWS, 256, 1024, nullptr, nullptr, nullptr, nullptr, nullptr);
  gemm128<0, true><<<dim3(1, ROWS / 128), dim3(256), 0, stream>>>(
      x, Wk, kii, ROWS, 64, 1024, nullptr, nullptr, nullptr, nullptr, nullptr);
  gemm128<0, true><<<dim3(1, ROWS / 128), dim3(256), 0, stream>>>(
      x, Ww, wI, ROWS, 4, 1024, nullptr, nullptr, nullptr, nullptr, nullptr);

  idx_topk_k<<<dim3(SS, BB), dim3(256), 0, stream>>>(qi, kii, wI, sel);
  attn_k<<<dim3(SS, BB), dim3(256), 0, stream>>>(Qr, Kh, Vh, sel, attnO);

  // out = attn @ Wo
  gemm128<0, false><<<dim3(1024 / 128, ROWS / 128), dim3(256), 0, stream>>>(
      attnO, Wo, out, ROWS, 1024, 1024, nullptr, nullptr, nullptr, nullptr, nullptr);
}

// Round 4
// 1206.607 us; speedup vs baseline: 1.5320x; 1.1892x over previous
//
#include <hip/hip_runtime.h>
#include <hip/hip_fp16.h>
#include <hip/hip_bf16.h>
#include <math.h>

#define BB 2
#define SS 2048
#define HH 16
#define TOPK 512
#define ROWS (BB*SS)
#define KDIM 1024
#define KP 3072      // 3*KDIM (split-bf16 tripled K)

using bf16x8 = __attribute__((ext_vector_type(8))) short;
using f32x4  = __attribute__((ext_vector_type(4))) float;

__device__ __forceinline__ void split_bf16(float f, short& hi, short& lo) {
  __hip_bfloat16 h = __float2bfloat16(f);
  float fh = __bfloat162float(h);
  __hip_bfloat16 l = __float2bfloat16(f - fh);
  hi = *reinterpret_cast<short*>(&h);
  lo = *reinterpret_cast<short*>(&l);
}

__device__ __forceinline__ unsigned fkey(float f) {
  unsigned u = __float_as_uint(f);
  if ((u << 1) == 0u) u = 0u;             // canonicalize -0.0 -> +0.0
  return (u & 0x80000000u) ? ~u : (u | 0x80000000u);
}

__global__ void rope_tab_k(float* __restrict__ ct, float* __restrict__ st) {
  int idx = blockIdx.x * blockDim.x + threadIdx.x;
  if (idx >= SS * 32) return;
  int s = idx >> 5, j = idx & 31;
  float theta = 1.0f / powf(10000.0f, (float)(2 * j) / 64.0f);
  float ang = (float)s * theta;
  float sv, cv;
  sincosf(ang, &sv, &cv);
  ct[idx] = cv;
  st[idx] = sv;
}

// X[M][1024] fp32 -> A[M][3072] bf16 triplets (hi,hi,lo)
__global__ __launch_bounds__(256) void pack_a_k(
    const float* __restrict__ X, short* __restrict__ A, int total4)
{
  int idx = blockIdx.x * 256 + threadIdx.x;
  if (idx >= total4) return;
  float4 v = ((const float4*)X)[idx];
  float a4[4] = {v.x, v.y, v.z, v.w};
  short o[12];
#pragma unroll
  for (int j = 0; j < 4; ++j) {
    short hs, ls; split_bf16(a4[j], hs, ls);
    o[3*j] = hs; o[3*j+1] = hs; o[3*j+2] = ls;
  }
  short* op = A + (size_t)idx * 12;
  *(short4*)(op)     = *(short4*)&o[0];
  *(short4*)(op + 4) = *(short4*)&o[4];
  *(short4*)(op + 8) = *(short4*)&o[8];
}

// W[K=1024][Nw] fp32 -> BT rows [n][3072] bf16 triplets (hi,lo,hi), transposed via LDS tile
__global__ __launch_bounds__(256) void pack_bt_k(
    const float* __restrict__ W, short* __restrict__ BT, int Nw)
{
  __shared__ float tile[32][33];
  int kb = blockIdx.y * 32, nb = blockIdx.x * 32;
  int tx = threadIdx.x & 31, ty = threadIdx.x >> 5;
  for (int yy = ty; yy < 32; yy += 8) {
    float v = 0.f;
    if (nb + tx < Nw) v = W[(size_t)(kb + yy) * Nw + nb + tx];
    tile[yy][tx] = v;
  }
  __syncthreads();
  for (int yy = ty; yy < 32; yy += 8) {
    int n = nb + yy;
    if (n >= Nw) continue;
    int k = kb + tx;
    float f = tile[tx][yy];
    short hs, ls; split_bf16(f, hs, ls);
    short* orow = BT + (size_t)n * KP + 3 * k;
    orow[0] = hs; orow[1] = ls; orow[2] = hs;
  }
}

// bf16 MFMA GEMM: C[M][N] = A[M][Kp] * BT[N][Kp]^T. 128x128 tile, BK=64, 4 waves.
__global__ __launch_bounds__(256) void gemm_bf16(
    const short* __restrict__ A, const short* __restrict__ BT,
    float* __restrict__ C, int M, int N, int Kp)
{
  __shared__ short As[128 * 64];
  __shared__ short Bs[128 * 64];
  const int tid = threadIdx.x;
  const int lane = tid & 63;
  const int wv = tid >> 6;
  const int m0 = blockIdx.y * 128, n0 = blockIdx.x * 128;
  const int wr = (wv >> 1) * 64, wc = (wv & 1) * 64;
  f32x4 acc[4][4];
#pragma unroll
  for (int i = 0; i < 4; ++i)
#pragma unroll
    for (int j = 0; j < 4; ++j)
#pragma unroll
      for (int r = 0; r < 4; ++r) acc[i][j][r] = 0.0f;

  const int rsel = lane & 15;
  for (int k0 = 0; k0 < Kp; k0 += 64) {
#pragma unroll
    for (int q = 0; q < 4; ++q) {
      int c = q * 256 + tid;
      int row = c >> 3, col = (c & 7) * 8;
      *(bf16x8*)&As[c * 8] = *(const bf16x8*)(A + (size_t)(m0 + row) * Kp + k0 + col);
      *(bf16x8*)&Bs[c * 8] = *(const bf16x8*)(BT + (size_t)(n0 + row) * Kp + k0 + col);
    }
    __syncthreads();
#pragma unroll
    for (int kk = 0; kk < 2; ++kk) {
      bf16x8 af[4], bfr[4];
      int kof = kk * 32 + (lane >> 4) * 8;
#pragma unroll
      for (int i = 0; i < 4; ++i) {
        af[i]  = *(const bf16x8*)&As[(wr + i * 16 + rsel) * 64 + kof];
        bfr[i] = *(const bf16x8*)&Bs[(wc + i * 16 + rsel) * 64 + kof];
      }
#pragma unroll
      for (int i = 0; i < 4; ++i)
#pragma unroll
        for (int j = 0; j < 4; ++j)
          acc[i][j] = __builtin_amdgcn_mfma_f32_16x16x32_bf16(af[i], bfr[j], acc[i][j], 0, 0, 0);
    }
    __syncthreads();
  }
  const int er = m0 + wr + (lane >> 4) * 4;
  const int ec = n0 + wc + rsel;
#pragma unroll
  for (int i = 0; i < 4; ++i)
#pragma unroll
    for (int j = 0; j < 4; ++j)
#pragma unroll
      for (int r = 0; r < 4; ++r)
        C[(size_t)(er + i * 16 + r) * N + ec + j * 16] = acc[i][j][r];
}

// fp32 GEMM (for the precision-critical indexer projections), 128x128 tile, BK=16.
template<bool BND>
__global__ __launch_bounds__(256) void gemm128f(
    const float* __restrict__ A, const float* __restrict__ Bw, float* __restrict__ C,
    int M, int N, int K)
{
  __shared__ float As[16][132];
  __shared__ float Bs[16][132];
  int n0 = blockIdx.x * 128, m0 = blockIdx.y * 128;
  int tid = threadIdx.x;
  int tm = (tid >> 4) << 3;
  int tn = (tid & 15) << 3;
  float acc[8][8];
#pragma unroll
  for (int i = 0; i < 8; ++i)
#pragma unroll
    for (int j = 0; j < 8; ++j) acc[i][j] = 0.0f;

  for (int k0 = 0; k0 < K; k0 += 16) {
#pragma unroll
    for (int q = 0; q < 2; ++q) {
      int lin = tid * 4 + q * 1024;
      int row = lin >> 4, kk = lin & 15;
      float4 av = *(const float4*)(A + (size_t)(m0 + row) * K + k0 + kk);
      As[kk + 0][row] = av.x; As[kk + 1][row] = av.y;
      As[kk + 2][row] = av.z; As[kk + 3][row] = av.w;
      int bk = lin >> 7, bc = lin & 127;
      float4 bv;
      if (!BND || (n0 + bc) < N)
        bv = *(const float4*)(Bw + (size_t)(k0 + bk) * N + n0 + bc);
      else
        bv = make_float4(0.f, 0.f, 0.f, 0.f);
      *(float4*)&Bs[bk][bc] = bv;
    }
    __syncthreads();
#pragma unroll
    for (int k = 0; k < 16; ++k) {
      float a[8], bb[8];
      *(float4*)&a[0]  = *(const float4*)&As[k][tm];
      *(float4*)&a[4]  = *(const float4*)&As[k][tm + 4];
      *(float4*)&bb[0] = *(const float4*)&Bs[k][tn];
      *(float4*)&bb[4] = *(const float4*)&Bs[k][tn + 4];
#pragma unroll
      for (int i = 0; i < 8; ++i)
#pragma unroll
        for (int j = 0; j < 8; ++j)
          acc[i][j] = fmaf(a[i], bb[j], acc[i][j]);
    }
    __syncthreads();
  }
#pragma unroll
  for (int i = 0; i < 8; ++i) {
    size_t m = (size_t)(m0 + tm + i);
    float* crow = C + m * (size_t)N;
#pragma unroll
    for (int jc = 0; jc < 2; ++jc) {
      int cb = n0 + tn + jc * 4;
      if (!BND || cb < N) {
        *(float4*)(crow + cb) = make_float4(acc[i][jc*4], acc[i][jc*4+1],
                                            acc[i][jc*4+2], acc[i][jc*4+3]);
      }
    }
  }
}

// C[M][3072] -> RoPE(q,k) + fp16 cast; Qr fp32, Kh/Vh fp16
__global__ __launch_bounds__(256) void qkv_post_k(
    const float* __restrict__ C, const float* __restrict__ ct, const float* __restrict__ st,
    float* __restrict__ Qr, __half* __restrict__ Kh, __half* __restrict__ Vh)
{
  int idx = blockIdx.x * 256 + threadIdx.x;
  if (idx >= ROWS * 384) return;
  int m = idx / 384;
  int g = idx - m * 384;
  int col0 = g * 8;
  const float* cp = C + (size_t)m * 3072 + col0;
  float4 v0 = *(const float4*)cp;
  float4 v1 = *(const float4*)(cp + 4);
  float a[8] = {v0.x, v0.y, v0.z, v0.w, v1.x, v1.y, v1.z, v1.w};
  int sec = col0 >> 10;
  int cin = col0 & 1023;
  size_t orow = (size_t)m * 1024 + cin;
  if (sec == 2) {
    __half2 hh[4];
#pragma unroll
    for (int c = 0; c < 4; ++c) hh[c] = __floats2half2_rn(a[2*c], a[2*c+1]);
    *(float4*)(Vh + orow) = *(float4*)hh;
  } else {
    int t = m & (SS - 1);
    int jb = (cin & 63) >> 1;
    float o[8];
#pragma unroll
    for (int c = 0; c < 4; ++c) {
      float cv = ct[t * 32 + jb + c], sv = st[t * 32 + jb + c];
      float x1 = a[2*c], x2 = a[2*c+1];
      o[2*c]     = x1 * cv - x2 * sv;
      o[2*c+1]   = x2 * cv + x1 * sv;
    }
    if (sec == 0) {
      *(float4*)(Qr + orow)     = make_float4(o[0], o[1], o[2], o[3]);
      *(float4*)(Qr + orow + 4) = make_float4(o[4], o[5], o[6], o[7]);
    } else {
      __half2 hh[4];
#pragma unroll
      for (int c = 0; c < 4; ++c) hh[c] = __floats2half2_rn(o[2*c], o[2*c+1]);
      *(float4*)(Kh + orow) = *(float4*)hh;
    }
  }
}

// Per (b,t): indexer scores for s<=t, exact top-512 (stable, lowest-index ties).
__global__ __launch_bounds__(256) void idx_topk_k(
    const float* __restrict__ qi, const float* __restrict__ ki,
    const float* __restrict__ wI, int* __restrict__ sel)
{
  int t = blockIdx.x, b = blockIdx.y;
  int tid = threadIdx.x;
  int* srow = sel + ((size_t)b * SS + t) * TOPK;
  if (t < TOPK) {  // -1e9 ties => selection is exactly [0..511]
    for (int i = tid; i < TOPK; i += 256) srow[i] = i;
    return;
  }
  __shared__ float sc[SS];
  __shared__ unsigned hist[256];
  __shared__ unsigned hs[256];
  __shared__ unsigned s_bsel, s_above, s_cnt;

  const float4* qrow = (const float4*)(qi + ((size_t)b * SS + t) * 256);
  const float* wrow = wI + ((size_t)b * SS + t) * 4;
  float w0 = wrow[0], w1 = wrow[1], w2 = wrow[2], w3 = wrow[3];

  for (int s = tid; s <= t; s += 256) {
    const float4* kp = (const float4*)(ki + ((size_t)b * SS + s) * 64);
    float a0 = 0.f, a1 = 0.f, a2 = 0.f, a3 = 0.f;
#pragma unroll
    for (int d4 = 0; d4 < 16; ++d4) {
      float4 kv = kp[d4];
      float4 q0 = qrow[d4];
      float4 q1 = qrow[16 + d4];
      float4 q2 = qrow[32 + d4];
      float4 q3 = qrow[48 + d4];
      a0 += q0.x * kv.x + q0.y * kv.y + q0.z * kv.z + q0.w * kv.w;
      a1 += q1.x * kv.x + q1.y * kv.y + q1.z * kv.z + q1.w * kv.w;
      a2 += q2.x * kv.x + q2.y * kv.y + q2.z * kv.z + q2.w * kv.w;
      a3 += q3.x * kv.x + q3.y * kv.y + q3.z * kv.z + q3.w * kv.w;
    }
    float v = fmaxf(a0, 0.f) * w0 + fmaxf(a1, 0.f) * w1 +
              fmaxf(a2, 0.f) * w2 + fmaxf(a3, 0.f) * w3;
    sc[s] = v;
  }
  __syncthreads();

  unsigned krem = TOPK;
  unsigned prefix = 0;
#pragma unroll 1
  for (int p = 0; p < 4; ++p) {
    int shift = 24 - 8 * p;
    unsigned maskAbove = (p == 0) ? 0u : (0xFFFFFFFFu << (shift + 8));
    hist[tid] = 0u;
    __syncthreads();
    for (int s = tid; s <= t; s += 256) {
      unsigned key = fkey(sc[s]);
      if ((key & maskAbove) == prefix)
        atomicAdd(&hist[(key >> shift) & 255], 1u);
    }
    __syncthreads();
    hs[tid] = hist[tid];
    __syncthreads();
#pragma unroll 1
    for (int off = 1; off < 256; off <<= 1) {
      unsigned v = (tid + off < 256) ? hs[tid + off] : 0u;
      __syncthreads();
      hs[tid] += v;
      __syncthreads();
    }
    unsigned mine = hs[tid];
    unsigned nxt = (tid < 255) ? hs[tid + 1] : 0u;
    if (mine >= krem && nxt < krem) { s_bsel = (unsigned)tid; s_above = nxt; }
    __syncthreads();
    prefix |= (s_bsel << shift);
    krem -= s_above;
    __syncthreads();
  }

  unsigned Tkey = prefix;
  unsigned kfin = krem;
  if (tid == 0) s_cnt = 0u;
  __syncthreads();
  for (int s = tid; s <= t; s += 256) {
    if (fkey(sc[s]) > Tkey) {
      unsigned pp = atomicAdd(&s_cnt, 1u);
      srow[pp] = s;
    }
  }
  __syncthreads();
  unsigned cgt = s_cnt;
  if (tid < 64) {
    unsigned taken = 0;
    for (int s0 = 0; s0 <= t && taken < kfin; s0 += 64) {
      int s = s0 + tid;
      bool pred = (s <= t) && (fkey(sc[s]) == Tkey);
      unsigned long long mba = __ballot(pred);
      unsigned pre = (unsigned)__popcll(mba & ((1ull << tid) - 1ull));
      if (pred && (taken + pre) < kfin) srow[cgt + taken + pre] = s;
      taken += (unsigned)__popcll(mba);
    }
  }
}

// Gather attention: one workgroup per (b,t). K/V fp16 in (b,s,h*64) layout.
__global__ __launch_bounds__(256) void attn_k(
    const float* __restrict__ Qr, const __half* __restrict__ Kh, const __half* __restrict__ Vh,
    const int* __restrict__ sel, float* __restrict__ attnO)
{
  int t = blockIdx.x, b = blockIdx.y;
  int tid = threadIdx.x;
  int lane = tid & 63;
  int wv = tid >> 6;
  __shared__ float P[TOPK][17];
  __shared__ int sidx[TOPK];
  __shared__ float denomS[16];

  if (t < TOPK) {
    for (int i = tid; i < TOPK; i += 256) sidx[i] = i;
  } else {
    const int* srow = sel + ((size_t)b * SS + t) * TOPK;
    for (int i = tid; i < TOPK; i += 256) sidx[i] = srow[i];
  }
  const float* qrow = Qr + ((size_t)b * SS + t) * 1024 + lane * 16;
  float q[16];
  *(float4*)&q[0]  = *(const float4*)(qrow);
  *(float4*)&q[4]  = *(const float4*)(qrow + 4);
  *(float4*)&q[8]  = *(const float4*)(qrow + 8);
  *(float4*)&q[12] = *(const float4*)(qrow + 12);
  __syncthreads();

  int h4 = lane >> 2;
  const size_t brow = (size_t)b * SS;
  for (int i = wv * 128; i < wv * 128 + 128; i += 2) {
    int s0 = sidx[i], s1 = sidx[i + 1];
    const __half2* kp0 = (const __half2*)(Kh + (brow + s0) * 1024 + lane * 16);
    const __half2* kp1 = (const __half2*)(Kh + (brow + s1) * 1024 + lane * 16);
    float4 ra0 = *(const float4*)(kp0);
    float4 ra1 = *(const float4*)(kp0 + 4);
    float4 rb0 = *(const float4*)(kp1);
    float4 rb1 = *(const float4*)(kp1 + 4);
    const __half2* ha0 = (const __half2*)&ra0;
    const __half2* ha1 = (const __half2*)&ra1;
    const __half2* hb0 = (const __half2*)&rb0;
    const __half2* hb1 = (const __half2*)&rb1;
    float d0 = 0.f, d1 = 0.f;
#pragma unroll
    for (int u = 0; u < 4; ++u) {
      float2 f = __half22float2(ha0[u]);
      d0 = fmaf(q[2*u], f.x, d0); d0 = fmaf(q[2*u+1], f.y, d0);
      float2 g = __half22float2(ha1[u]);
      d0 = fmaf(q[8+2*u], g.x, d0); d0 = fmaf(q[8+2*u+1], g.y, d0);
      float2 fb = __half22float2(hb0[u]);
      d1 = fmaf(q[2*u], fb.x, d1); d1 = fmaf(q[2*u+1], fb.y, d1);
      float2 gb = __half22float2(hb1[u]);
      d1 = fmaf(q[8+2*u], gb.x, d1); d1 = fmaf(q[8+2*u+1], gb.y, d1);
    }
    d0 += __shfl_xor(d0, 1); d0 += __shfl_xor(d0, 2);
    d1 += __shfl_xor(d1, 1); d1 += __shfl_xor(d1, 2);
    if ((lane & 3) == 0) {
      P[i][h4]     = d0 * 0.125f;
      P[i + 1][h4] = d1 * 0.125f;
    }
  }
  __syncthreads();

  int h = tid >> 4, i0 = tid & 15;
  float mx = -3.0e38f;
  for (int i = i0; i < TOPK; i += 16) mx = fmaxf(mx, P[i][h]);
#pragma unroll
  for (int off = 1; off < 16; off <<= 1) mx = fmaxf(mx, __shfl_xor(mx, off));
  float sum = 0.f;
  for (int i = i0; i < TOPK; i += 16) {
    float e = __expf(P[i][h] - mx);
    P[i][h] = e;
    sum += e;
  }
#pragma unroll
  for (int off = 1; off < 16; off <<= 1) sum += __shfl_xor(sum, off);
  if (i0 == 0) denomS[h] = sum;
  __syncthreads();

  int dq = (tid & 15) << 2;
  size_t hoff = h * 64 + dq;
  float ax = 0.f, ay = 0.f, az = 0.f, aw = 0.f;
  for (int i = 0; i < TOPK; i += 4) {
#pragma unroll
    for (int u = 0; u < 4; ++u) {
      int s = sidx[i + u];
      float pv = P[i + u][h];
      float2 rv = *(const float2*)(Vh + (brow + s) * 1024 + hoff);
      const __half2* hv = (const __half2*)&rv;
      float2 v0 = __half22float2(hv[0]);
      float2 v1 = __half22float2(hv[1]);
      ax = fmaf(pv, v0.x, ax);
      ay = fmaf(pv, v0.y, ay);
      az = fmaf(pv, v1.x, az);
      aw = fmaf(pv, v1.y, aw);
    }
  }
  float inv = 1.0f / denomS[h];
  *(float4*)(attnO + (brow + t) * 1024 + hoff) =
      make_float4(ax * inv, ay * inv, az * inv, aw * inv);
}

extern "C" void kernel_launch(void* const* d_in, const int* in_sizes, int n_in,
                              void* d_out, int out_size, void* d_ws, size_t ws_size,
                              hipStream_t stream) {
  const float* x    = (const float*)d_in[0];
  const float* Wqkv = (const float*)d_in[1];
  const float* Wo   = (const float*)d_in[2];
  const float* Wq   = (const float*)d_in[3];
  const float* Wk   = (const float*)d_in[4];
  const float* Ww   = (const float*)d_in[5];
  float* out = (float*)d_out;

  float* fws = (float*)d_ws;
  size_t o = 0;
  float*  Qr    = fws + o;             o += (size_t)ROWS * 1024;       // 4M fl
  __half* Kh    = (__half*)(fws + o);  o += (size_t)ROWS * 512;        // 2.1M fl
  __half* Vh    = (__half*)(fws + o);  o += (size_t)ROWS * 512;
  int*    sel   = (int*)(fws + o);     o += (size_t)ROWS * TOPK;       // 2.1M fl
  float*  ct    = fws + o;             o += (size_t)SS * 32;
  float*  st    = fws + o;             o += (size_t)SS * 32;
  float*  qi    = fws + o;             o += (size_t)ROWS * 256;        // 1.05M fl
  float*  kii   = fws + o;             o += (size_t)ROWS * 64;
  float*  wI    = fws + o;             o += (size_t)ROWS * 4;
  short*  BTwo  = (short*)(fws + o);   o += (size_t)1024 * KP / 2;     // 1.57M fl
  short*  BTq   = (short*)(fws + o);   o += (size_t)3072 * KP / 2;     // 4.72M fl
  short*  Ax    = (short*)(fws + o);                                   // 6.29M fl region:
  float*  attnO = fws + o;             o += (size_t)ROWS * KP / 2;     //  attnO aliases Ax (Ax dead after qkv gemm)
  float*  Cbuf  = fws + o;                                             // 12.6M fl region:
  short*  Aattn = (short*)(fws + o);   o += (size_t)ROWS * 3072;       //  Aattn aliases C (C dead after qkv_post/idx)

  rope_tab_k<<<dim3((SS * 32 + 255) / 256), dim3(256), 0, stream>>>(ct, st);

  // packs for the two MFMA GEMMs
  pack_a_k<<<dim3(ROWS * KDIM / 4 / 256), dim3(256), 0, stream>>>(x, Ax, ROWS * KDIM / 4);
  pack_bt_k<<<dim3(3072 / 32, 32), dim3(256), 0, stream>>>(Wqkv, BTq, 3072);
  pack_bt_k<<<dim3(1024 / 32, 32), dim3(256), 0, stream>>>(Wo, BTwo, 1024);

  // qkv GEMM (split-bf16 MFMA): C[4096][3072] = x * Wqkv
  gemm_bf16<<<dim3(3072 / 128, ROWS / 128), dim3(256), 0, stream>>>(
      Ax, BTq, Cbuf, ROWS, 3072, KP);
  qkv_post_k<<<dim3((ROWS * 384 + 255) / 256), dim3(256), 0, stream>>>(Cbuf, ct, st, Qr, Kh, Vh);

  // indexer projections in fp32 (precision-critical: feeds exact top-k)
  gemm128f<false><<<dim3(2, ROWS / 128), dim3(256), 0, stream>>>(x, Wq, qi, ROWS, 256, 1024);
  gemm128f<true><<<dim3(1, ROWS / 128), dim3(256), 0, stream>>>(x, Wk, kii, ROWS, 64, 1024);
  gemm128f<true><<<dim3(1, ROWS / 128), dim3(256), 0, stream>>>(x, Ww, wI, ROWS, 4, 1024);

  idx_topk_k<<<dim3(SS, BB), dim3(256), 0, stream>>>(qi, kii, wI, sel);
  attn_k<<<dim3(SS, BB), dim3(256), 0, stream>>>(Qr, Kh, Vh, sel, attnO);

  // out = attn @ Wo (split-bf16 MFMA)
  pack_a_k<<<dim3(ROWS * KDIM / 4 / 256), dim3(256), 0, stream>>>(attnO, Aattn, ROWS * KDIM / 4);
  gemm_bf16<<<dim3(1024 / 128, ROWS / 128), dim3(256), 0, stream>>>(
      Aattn, BTwo, out, ROWS, 1024, KP);
}

// Round 5
// 1197.773 us; speedup vs baseline: 1.5433x; 1.0074x over previous
//
#include <hip/hip_runtime.h>
#include <hip/hip_fp16.h>
#include <hip/hip_bf16.h>
#include <math.h>

#define BB 2
#define SS 2048
#define HH 16
#define TOPK 512
#define ROWS (BB*SS)
#define KDIM 1024
#define KP 3072      // 3*KDIM (split-bf16 tripled K)

using bf16x8 = __attribute__((ext_vector_type(8))) short;
using f32x4  = __attribute__((ext_vector_type(4))) float;
typedef _Float16 h2f __attribute__((ext_vector_type(2)));
typedef unsigned int u32;

__device__ __forceinline__ float fdot2(u32 a, u32 b, float c) {
#if defined(__has_builtin) && __has_builtin(__builtin_amdgcn_fdot2)
  return __builtin_amdgcn_fdot2(__builtin_bit_cast(h2f, a), __builtin_bit_cast(h2f, b), c, false);
#else
  float d;
  asm volatile("v_dot2_f32_f16 %0, %1, %2, %3" : "=v"(d) : "v"(a), "v"(b), "v"(c));
  return d;
#endif
}

__device__ __forceinline__ u32 pkh2(float a, float b) {
  __half2 h = __floats2half2_rn(a, b);
  return *reinterpret_cast<u32*>(&h);
}

__device__ __forceinline__ void gload16(const void* g, void* l) {
  __builtin_amdgcn_global_load_lds(
      (const __attribute__((address_space(1))) u32*)g,
      (__attribute__((address_space(3))) u32*)l, 16, 0, 0);
}

__device__ __forceinline__ void split_bf16(float f, short& hi, short& lo) {
  __hip_bfloat16 h = __float2bfloat16(f);
  float fh = __bfloat162float(h);
  __hip_bfloat16 l = __float2bfloat16(f - fh);
  hi = *reinterpret_cast<short*>(&h);
  lo = *reinterpret_cast<short*>(&l);
}

__device__ __forceinline__ unsigned fkey(float f) {
  unsigned u = __float_as_uint(f);
  if ((u << 1) == 0u) u = 0u;             // canonicalize -0.0 -> +0.0
  return (u & 0x80000000u) ? ~u : (u | 0x80000000u);
}

__global__ void rope_tab_k(float* __restrict__ ct, float* __restrict__ st) {
  int idx = blockIdx.x * blockDim.x + threadIdx.x;
  if (idx >= SS * 32) return;
  int s = idx >> 5, j = idx & 31;
  float theta = 1.0f / powf(10000.0f, (float)(2 * j) / 64.0f);
  float ang = (float)s * theta;
  float sv, cv;
  sincosf(ang, &sv, &cv);
  ct[idx] = cv;
  st[idx] = sv;
}

// X[M][1024] fp32 -> A[M][3072] bf16 triplets (hi,hi,lo)
__global__ __launch_bounds__(256) void pack_a_k(
    const float* __restrict__ X, short* __restrict__ A, int total4)
{
  int idx = blockIdx.x * 256 + threadIdx.x;
  if (idx >= total4) return;
  float4 v = ((const float4*)X)[idx];
  float a4[4] = {v.x, v.y, v.z, v.w};
  short o[12];
#pragma unroll
  for (int j = 0; j < 4; ++j) {
    short hs, ls; split_bf16(a4[j], hs, ls);
    o[3*j] = hs; o[3*j+1] = hs; o[3*j+2] = ls;
  }
  short* op = A + (size_t)idx * 12;
  *(short4*)(op)     = *(short4*)&o[0];
  *(short4*)(op + 4) = *(short4*)&o[4];
  *(short4*)(op + 8) = *(short4*)&o[8];
}

// W[K=1024][Nw] fp32 -> BT rows [n][3072] bf16 triplets (hi,lo,hi)
__global__ __launch_bounds__(256) void pack_bt_k(
    const float* __restrict__ W, short* __restrict__ BT, int Nw)
{
  __shared__ float tile[32][33];
  int kb = blockIdx.y * 32, nb = blockIdx.x * 32;
  int tx = threadIdx.x & 31, ty = threadIdx.x >> 5;
  for (int yy = ty; yy < 32; yy += 8) {
    float v = 0.f;
    if (nb + tx < Nw) v = W[(size_t)(kb + yy) * Nw + nb + tx];
    tile[yy][tx] = v;
  }
  __syncthreads();
  for (int yy = ty; yy < 32; yy += 8) {
    int n = nb + yy;
    if (n >= Nw) continue;
    int k = kb + tx;
    float f = tile[tx][yy];
    short hs, ls; split_bf16(f, hs, ls);
    short* orow = BT + (size_t)n * KP + 3 * k;
    orow[0] = hs; orow[1] = ls; orow[2] = hs;
  }
}

// bf16 MFMA GEMM: C[M][N] = A[M][Kp]*BT[N][Kp]^T. 128x128, BK=64, 4 waves,
// global_load_lds (width=16) staging.
__global__ __launch_bounds__(256) void gemm_bf16(
    const short* __restrict__ A, const short* __restrict__ BT,
    float* __restrict__ C, int M, int N, int Kp)
{
  __shared__ short As[128 * 64];
  __shared__ short Bs[128 * 64];
  const int tid = threadIdx.x;
  const int lane = tid & 63;
  const int wv = tid >> 6;
  const int m0 = blockIdx.y * 128, n0 = blockIdx.x * 128;
  const int wr = (wv >> 1) * 64, wc = (wv & 1) * 64;
  f32x4 acc[4][4];
#pragma unroll
  for (int i = 0; i < 4; ++i)
#pragma unroll
    for (int j = 0; j < 4; ++j)
#pragma unroll
      for (int r = 0; r < 4; ++r) acc[i][j][r] = 0.0f;

  const int rsel = lane & 15;
  const int lrow = lane >> 3;          // 0..7
  const int lcol = (lane & 7) * 8;     // shorts
  for (int k0 = 0; k0 < Kp; k0 += 64) {
#pragma unroll
    for (int q = 0; q < 4; ++q) {
      int c = wv * 4 + q;              // chunk 0..15 (8 rows each)
      int row = c * 8 + lrow;
      gload16(A  + (size_t)(m0 + row) * Kp + k0 + lcol, &As[c * 512]);
      gload16(BT + (size_t)(n0 + row) * Kp + k0 + lcol, &Bs[c * 512]);
    }
    __syncthreads();
#pragma unroll
    for (int kk = 0; kk < 2; ++kk) {
      bf16x8 af[4], bfr[4];
      int kof = kk * 32 + (lane >> 4) * 8;
#pragma unroll
      for (int i = 0; i < 4; ++i) {
        af[i]  = *(const bf16x8*)&As[(wr + i * 16 + rsel) * 64 + kof];
        bfr[i] = *(const bf16x8*)&Bs[(wc + i * 16 + rsel) * 64 + kof];
      }
#pragma unroll
      for (int i = 0; i < 4; ++i)
#pragma unroll
        for (int j = 0; j < 4; ++j)
          acc[i][j] = __builtin_amdgcn_mfma_f32_16x16x32_bf16(af[i], bfr[j], acc[i][j], 0, 0, 0);
    }
    __syncthreads();
  }
  const int er = m0 + wr + (lane >> 4) * 4;
  const int ec = n0 + wc + rsel;
#pragma unroll
  for (int i = 0; i < 4; ++i)
#pragma unroll
    for (int j = 0; j < 4; ++j)
#pragma unroll
      for (int r = 0; r < 4; ++r)
        C[(size_t)(er + i * 16 + r) * N + ec + j * 16] = acc[i][j][r];
}

// fp32 GEMM for the precision-critical indexer projections, 128x128, BK=16.
template<bool BND>
__global__ __launch_bounds__(256) void gemm128f(
    const float* __restrict__ A, const float* __restrict__ Bw, float* __restrict__ C,
    int M, int N, int K)
{
  __shared__ float As[16][132];
  __shared__ float Bs[16][132];
  int n0 = blockIdx.x * 128, m0 = blockIdx.y * 128;
  int tid = threadIdx.x;
  int tm = (tid >> 4) << 3;
  int tn = (tid & 15) << 3;
  float acc[8][8];
#pragma unroll
  for (int i = 0; i < 8; ++i)
#pragma unroll
    for (int j = 0; j < 8; ++j) acc[i][j] = 0.0f;

  for (int k0 = 0; k0 < K; k0 += 16) {
#pragma unroll
    for (int q = 0; q < 2; ++q) {
      int lin = tid * 4 + q * 1024;
      int row = lin >> 4, kk = lin & 15;
      float4 av = *(const float4*)(A + (size_t)(m0 + row) * K + k0 + kk);
      As[kk + 0][row] = av.x; As[kk + 1][row] = av.y;
      As[kk + 2][row] = av.z; As[kk + 3][row] = av.w;
      int bk = lin >> 7, bc = lin & 127;
      float4 bv;
      if (!BND || (n0 + bc) < N)
        bv = *(const float4*)(Bw + (size_t)(k0 + bk) * N + n0 + bc);
      else
        bv = make_float4(0.f, 0.f, 0.f, 0.f);
      *(float4*)&Bs[bk][bc] = bv;
    }
    __syncthreads();
#pragma unroll
    for (int k = 0; k < 16; ++k) {
      float a[8], bb[8];
      *(float4*)&a[0]  = *(const float4*)&As[k][tm];
      *(float4*)&a[4]  = *(const float4*)&As[k][tm + 4];
      *(float4*)&bb[0] = *(const float4*)&Bs[k][tn];
      *(float4*)&bb[4] = *(const float4*)&Bs[k][tn + 4];
#pragma unroll
      for (int i = 0; i < 8; ++i)
#pragma unroll
        for (int j = 0; j < 8; ++j)
          acc[i][j] = fmaf(a[i], bb[j], acc[i][j]);
    }
    __syncthreads();
  }
#pragma unroll
  for (int i = 0; i < 8; ++i) {
    size_t m = (size_t)(m0 + tm + i);
    float* crow = C + m * (size_t)N;
#pragma unroll
    for (int jc = 0; jc < 2; ++jc) {
      int cb = n0 + tn + jc * 4;
      if (!BND || cb < N) {
        *(float4*)(crow + cb) = make_float4(acc[i][jc*4], acc[i][jc*4+1],
                                            acc[i][jc*4+2], acc[i][jc*4+3]);
      }
    }
  }
}

// C[M][3072] -> RoPE(q,k) + fp16 cast; Qh/Kh/Vh all fp16
__global__ __launch_bounds__(256) void qkv_post_k(
    const float* __restrict__ C, const float* __restrict__ ct, const float* __restrict__ st,
    __half* __restrict__ Qh, __half* __restrict__ Kh, __half* __restrict__ Vh)
{
  int idx = blockIdx.x * 256 + threadIdx.x;
  if (idx >= ROWS * 384) return;
  int m = idx / 384;
  int g = idx - m * 384;
  int col0 = g * 8;
  const float* cp = C + (size_t)m * 3072 + col0;
  float4 v0 = *(const float4*)cp;
  float4 v1 = *(const float4*)(cp + 4);
  float a[8] = {v0.x, v0.y, v0.z, v0.w, v1.x, v1.y, v1.z, v1.w};
  int sec = col0 >> 10;
  int cin = col0 & 1023;
  size_t orow = (size_t)m * 1024 + cin;
  if (sec == 2) {
    __half2 hh[4];
#pragma unroll
    for (int c = 0; c < 4; ++c) hh[c] = __floats2half2_rn(a[2*c], a[2*c+1]);
    *(float4*)(Vh + orow) = *(float4*)hh;
  } else {
    int t = m & (SS - 1);
    int jb = (cin & 63) >> 1;
    float o[8];
#pragma unroll
    for (int c = 0; c < 4; ++c) {
      float cv = ct[t * 32 + jb + c], sv = st[t * 32 + jb + c];
      float x1 = a[2*c], x2 = a[2*c+1];
      o[2*c]   = x1 * cv - x2 * sv;
      o[2*c+1] = x2 * cv + x1 * sv;
    }
    __half2 hh[4];
#pragma unroll
    for (int c = 0; c < 4; ++c) hh[c] = __floats2half2_rn(o[2*c], o[2*c+1]);
    __half* dst = (sec == 0) ? Qh : Kh;
    *(float4*)(dst + orow) = *(float4*)hh;
  }
}

// Per (b,t): indexer scores for s<=t, exact top-512 (stable, lowest-index ties).
__global__ __launch_bounds__(256) void idx_topk_k(
    const float* __restrict__ qi, const float* __restrict__ ki,
    const float* __restrict__ wI, int* __restrict__ sel)
{
  int t = blockIdx.x, b = blockIdx.y;
  int tid = threadIdx.x;
  int* srow = sel + ((size_t)b * SS + t) * TOPK;
  if (t < TOPK) {  // -1e9 ties => selection is exactly [0..511]
    for (int i = tid; i < TOPK; i += 256) srow[i] = i;
    return;
  }
  __shared__ float sc[SS];
  __shared__ unsigned hist[256];
  __shared__ unsigned hs[256];
  __shared__ unsigned s_bsel, s_above, s_cnt;

  const float4* qrow = (const float4*)(qi + ((size_t)b * SS + t) * 256);
  const float* wrow = wI + ((size_t)b * SS + t) * 4;
  float w0 = wrow[0], w1 = wrow[1], w2 = wrow[2], w3 = wrow[3];

  for (int s = tid; s <= t; s += 256) {
    const float4* kp = (const float4*)(ki + ((size_t)b * SS + s) * 64);
    float a0 = 0.f, a1 = 0.f, a2 = 0.f, a3 = 0.f;
#pragma unroll
    for (int d4 = 0; d4 < 16; ++d4) {
      float4 kv = kp[d4];
      float4 q0 = qrow[d4];
      float4 q1 = qrow[16 + d4];
      float4 q2 = qrow[32 + d4];
      float4 q3 = qrow[48 + d4];
      a0 += q0.x * kv.x + q0.y * kv.y + q0.z * kv.z + q0.w * kv.w;
      a1 += q1.x * kv.x + q1.y * kv.y + q1.z * kv.z + q1.w * kv.w;
      a2 += q2.x * kv.x + q2.y * kv.y + q2.z * kv.z + q2.w * kv.w;
      a3 += q3.x * kv.x + q3.y * kv.y + q3.z * kv.z + q3.w * kv.w;
    }
    float v = fmaxf(a0, 0.f) * w0 + fmaxf(a1, 0.f) * w1 +
              fmaxf(a2, 0.f) * w2 + fmaxf(a3, 0.f) * w3;
    sc[s] = v;
  }
  __syncthreads();

  unsigned krem = TOPK;
  unsigned prefix = 0;
#pragma unroll 1
  for (int p = 0; p < 4; ++p) {
    int shift = 24 - 8 * p;
    unsigned maskAbove = (p == 0) ? 0u : (0xFFFFFFFFu << (shift + 8));
    hist[tid] = 0u;
    __syncthreads();
    for (int s = tid; s <= t; s += 256) {
      unsigned key = fkey(sc[s]);
      if ((key & maskAbove) == prefix)
        atomicAdd(&hist[(key >> shift) & 255], 1u);
    }
    __syncthreads();
    hs[tid] = hist[tid];
    __syncthreads();
#pragma unroll 1
    for (int off = 1; off < 256; off <<= 1) {
      unsigned v = (tid + off < 256) ? hs[tid + off] : 0u;
      __syncthreads();
      hs[tid] += v;
      __syncthreads();
    }
    unsigned mine = hs[tid];
    unsigned nxt = (tid < 255) ? hs[tid + 1] : 0u;
    if (mine >= krem && nxt < krem) { s_bsel = (unsigned)tid; s_above = nxt; }
    __syncthreads();
    prefix |= (s_bsel << shift);
    krem -= s_above;
    __syncthreads();
  }

  unsigned Tkey = prefix;
  unsigned kfin = krem;
  if (tid == 0) s_cnt = 0u;
  __syncthreads();
  for (int s = tid; s <= t; s += 256) {
    if (fkey(sc[s]) > Tkey) {
      unsigned pp = atomicAdd(&s_cnt, 1u);
      srow[pp] = s;
    }
  }
  __syncthreads();
  unsigned cgt = s_cnt;
  if (tid < 64) {
    unsigned taken = 0;
    for (int s0 = 0; s0 <= t && taken < kfin; s0 += 64) {
      int s = s0 + tid;
      bool pred = (s <= t) && (fkey(sc[s]) == Tkey);
      unsigned long long mba = __ballot(pred);
      unsigned pre = (unsigned)__popcll(mba & ((1ull << tid) - 1ull));
      if (pred && (taken + pre) < kfin) srow[cgt + taken + pre] = s;
      taken += (unsigned)__popcll(mba);
    }
  }
}

// Gather attention: linear grid with XCD partition (b -> 4 XCDs each).
// Q/K/V fp16; QK via v_dot2_f32_f16; PV via v_perm + v_dot2.
__global__ __launch_bounds__(256) void attn_k(
    const __half* __restrict__ Qh, const __half* __restrict__ Kh, const __half* __restrict__ Vh,
    const int* __restrict__ sel, float* __restrict__ attnO)
{
  int bid = blockIdx.x;
  int xcd = bid & 7, jj0 = bid >> 3;
  int b = xcd >> 2;
  int t = (xcd & 3) * 512 + jj0;
  int tid = threadIdx.x;
  int lane = tid & 63;
  int wv = tid >> 6;
  __shared__ float P[TOPK][17];
  __shared__ int sidx[TOPK];
  __shared__ float denomS[16];

  if (t < TOPK) {
    for (int i = tid; i < TOPK; i += 256) sidx[i] = i;
  } else {
    const int* srow = sel + ((size_t)b * SS + t) * TOPK;
    for (int i = tid; i < TOPK; i += 256) sidx[i] = srow[i];
  }
  const size_t brow = (size_t)b * SS;
  const __half* qrow = Qh + (brow + t) * 1024 + lane * 16;
  u32 qq[8];
  *(float4*)&qq[0] = *(const float4*)(qrow);
  *(float4*)&qq[4] = *(const float4*)(qrow + 8);
  __syncthreads();

  int h4 = lane >> 2;
  for (int i = wv * 128; i < wv * 128 + 128; i += 2) {
    int s0 = sidx[i], s1 = sidx[i + 1];
    const __half* kp0 = Kh + (brow + s0) * 1024 + lane * 16;
    const __half* kp1 = Kh + (brow + s1) * 1024 + lane * 16;
    u32 ka[8], kb[8];
    *(float4*)&ka[0] = *(const float4*)(kp0);
    *(float4*)&ka[4] = *(const float4*)(kp0 + 8);
    *(float4*)&kb[0] = *(const float4*)(kp1);
    *(float4*)&kb[4] = *(const float4*)(kp1 + 8);
    float d0 = 0.f, d1 = 0.f;
#pragma unroll
    for (int u = 0; u < 8; ++u) {
      d0 = fdot2(qq[u], ka[u], d0);
      d1 = fdot2(qq[u], kb[u], d1);
    }
    d0 += __shfl_xor(d0, 1); d0 += __shfl_xor(d0, 2);
    d1 += __shfl_xor(d1, 1); d1 += __shfl_xor(d1, 2);
    if ((lane & 3) == 0) {
      P[i][h4]     = d0 * 0.125f;
      P[i + 1][h4] = d1 * 0.125f;
    }
  }
  __syncthreads();

  int h = tid >> 4, i0 = tid & 15;
  float mx = -3.0e38f;
  for (int i = i0; i < TOPK; i += 16) mx = fmaxf(mx, P[i][h]);
#pragma unroll
  for (int off = 1; off < 16; off <<= 1) mx = fmaxf(mx, __shfl_xor(mx, off));
  float sum = 0.f;
  u32 pk[16];
#pragma unroll
  for (int jj = 0; jj < 16; ++jj) {
    int i2 = i0 + 16 * jj;
    float e0 = __expf(P[2 * i2][h] - mx);
    float e1 = __expf(P[2 * i2 + 1][h] - mx);
    sum += e0 + e1;
    pk[jj] = pkh2(e0, e1);
  }
#pragma unroll
  for (int off = 1; off < 16; off <<= 1) sum += __shfl_xor(sum, off);
  if (i0 == 0) denomS[h] = sum;
  __syncthreads();                       // all raw-P reads done
  u32* Ph2u = (u32*)&P[0][0];            // reuse P storage: [256][17] half2 rows
#pragma unroll
  for (int jj = 0; jj < 16; ++jj) Ph2u[(i0 + 16 * jj) * 17 + h] = pk[jj];
  __syncthreads();

  // PV: thread (h, dq): 4 output dims; pairs of keys via perm+dot2
  int dq = (tid & 15) << 2;
  size_t hoff = (size_t)h * 64 + dq;
  const __half* vb = Vh + brow * 1024 + hoff;
  float a0 = 0.f, a1 = 0.f, a2 = 0.f, a3 = 0.f;
  for (int i2 = 0; i2 < 256; i2 += 2) {
#pragma unroll
    for (int u = 0; u < 2; ++u) {
      int ii = i2 + u;
      u32 pv = Ph2u[ii * 17 + h];
      int2 ss = *(const int2*)&sidx[2 * ii];
      float2 va = *(const float2*)(vb + (size_t)ss.x * 1024);
      float2 vw = *(const float2*)(vb + (size_t)ss.y * 1024);
      u32 A01 = __float_as_uint(va.x), A23 = __float_as_uint(va.y);
      u32 B01 = __float_as_uint(vw.x), B23 = __float_as_uint(vw.y);
      a0 = fdot2(pv, __builtin_amdgcn_perm(A01, B01, 0x01000504u), a0);
      a1 = fdot2(pv, __builtin_amdgcn_perm(A01, B01, 0x03020706u), a1);
      a2 = fdot2(pv, __builtin_amdgcn_perm(A23, B23, 0x01000504u), a2);
      a3 = fdot2(pv, __builtin_amdgcn_perm(A23, B23, 0x03020706u), a3);
    }
  }
  float inv = 1.0f / denomS[h];
  *(float4*)(attnO + (brow + t) * 1024 + hoff) =
      make_float4(a0 * inv, a1 * inv, a2 * inv, a3 * inv);
}

extern "C" void kernel_launch(void* const* d_in, const int* in_sizes, int n_in,
                              void* d_out, int out_size, void* d_ws, size_t ws_size,
                              hipStream_t stream) {
  const float* x    = (const float*)d_in[0];
  const float* Wqkv = (const float*)d_in[1];
  const float* Wo   = (const float*)d_in[2];
  const float* Wq   = (const float*)d_in[3];
  const float* Wk   = (const float*)d_in[4];
  const float* Ww   = (const float*)d_in[5];
  float* out = (float*)d_out;

  float* fws = (float*)d_ws;
  size_t o = 0;
  __half* Qh    = (__half*)(fws + o);  o += (size_t)ROWS * 512;
  __half* Kh    = (__half*)(fws + o);  o += (size_t)ROWS * 512;
  __half* Vh    = (__half*)(fws + o);  o += (size_t)ROWS * 512;
  int*    sel   = (int*)(fws + o);     o += (size_t)ROWS * TOPK;
  float*  ct    = fws + o;             o += (size_t)SS * 32;
  float*  st    = fws + o;             o += (size_t)SS * 32;
  float*  qi    = fws + o;             o += (size_t)ROWS * 256;
  float*  kii   = fws + o;             o += (size_t)ROWS * 64;
  float*  wI    = fws + o;             o += (size_t)ROWS * 4;
  short*  BTwo  = (short*)(fws + o);   o += (size_t)1024 * KP / 2;
  short*  BTq   = (short*)(fws + o);   o += (size_t)3072 * KP / 2;
  short*  Ax    = (short*)(fws + o);                                   // aliased region:
  float*  attnO = fws + o;             o += (size_t)ROWS * KP / 2;     //  attnO reuses Ax
  float*  Cbuf  = fws + o;                                             // aliased region:
  short*  Aattn = (short*)(fws + o);   o += (size_t)ROWS * 3072;       //  Aattn reuses Cbuf

  rope_tab_k<<<dim3((SS * 32 + 255) / 256), dim3(256), 0, stream>>>(ct, st);

  // packs for the two MFMA GEMMs
  pack_a_k<<<dim3(ROWS * KDIM / 4 / 256), dim3(256), 0, stream>>>(x, Ax, ROWS * KDIM / 4);
  pack_bt_k<<<dim3(3072 / 32, 32), dim3(256), 0, stream>>>(Wqkv, BTq, 3072);
  pack_bt_k<<<dim3(1024 / 32, 32), dim3(256), 0, stream>>>(Wo, BTwo, 1024);

  // qkv GEMM (split-bf16 MFMA): Cbuf[4096][3072] = x * Wqkv
  gemm_bf16<<<dim3(3072 / 128, ROWS / 128), dim3(256), 0, stream>>>(
      Ax, BTq, Cbuf, ROWS, 3072, KP);
  qkv_post_k<<<dim3((ROWS * 384 + 255) / 256), dim3(256), 0, stream>>>(Cbuf, ct, st, Qh, Kh, Vh);

  // indexer projections in fp32 (precision-critical: feeds exact top-k)
  gemm128f<false><<<dim3(2, ROWS / 128), dim3(256), 0, stream>>>(x, Wq, qi, ROWS, 256, 1024);
  gemm128f<true><<<dim3(1, ROWS / 128), dim3(256), 0, stream>>>(x, Wk, kii, ROWS, 64, 1024);
  gemm128f<true><<<dim3(1, ROWS / 128), dim3(256), 0, stream>>>(x, Ww, wI, ROWS, 4, 1024);

  idx_topk_k<<<dim3(SS, BB), dim3(256), 0, stream>>>(qi, kii, wI, sel);
  attn_k<<<dim3(ROWS), dim3(256), 0, stream>>>(Qh, Kh, Vh, sel, attnO);

  // out = attn @ Wo (split-bf16 MFMA)
  pack_a_k<<<dim3(ROWS * KDIM / 4 / 256), dim3(256), 0, stream>>>(attnO, Aattn, ROWS * KDIM / 4);
  gemm_bf16<<<dim3(1024 / 128, ROWS / 128), dim3(256), 0, stream>>>(
      Aattn, BTwo, out, ROWS, 1024, KP);
}

// Round 6
// 929.667 us; speedup vs baseline: 1.9883x; 1.2884x over previous
//
#include <hip/hip_runtime.h>
#include <hip/hip_fp16.h>
#include <hip/hip_bf16.h>
#include <math.h>

#define BB 2
#define SS 2048
#define HH 16
#define TOPK 512
#define ROWS (BB*SS)
#define KDIM 1024
#define KP 3072      // 3*KDIM (split-bf16 tripled K)
#define NCAT 324     // 256 qi | 64 ki | 4 w

using bf16x8 = __attribute__((ext_vector_type(8))) short;
using f32x4  = __attribute__((ext_vector_type(4))) float;
typedef _Float16 h2f __attribute__((ext_vector_type(2)));
typedef unsigned int u32;

__device__ __forceinline__ float fdot2(u32 a, u32 b, float c) {
#if defined(__has_builtin) && __has_builtin(__builtin_amdgcn_fdot2)
  return __builtin_amdgcn_fdot2(__builtin_bit_cast(h2f, a), __builtin_bit_cast(h2f, b), c, false);
#else
  float d;
  asm volatile("v_dot2_f32_f16 %0, %1, %2, %3" : "=v"(d) : "v"(a), "v"(b), "v"(c));
  return d;
#endif
}

__device__ __forceinline__ u32 pkh2(float a, float b) {
  __half2 h = __floats2half2_rn(a, b);
  return *reinterpret_cast<u32*>(&h);
}

__device__ __forceinline__ void gload16(const void* g, void* l) {
  __builtin_amdgcn_global_load_lds(
      (const __attribute__((address_space(1))) u32*)g,
      (__attribute__((address_space(3))) u32*)l, 16, 0, 0);
}

__device__ __forceinline__ void split_bf16(float f, short& hi, short& lo) {
  __hip_bfloat16 h = __float2bfloat16(f);
  float fh = __bfloat162float(h);
  __hip_bfloat16 l = __float2bfloat16(f - fh);
  hi = *reinterpret_cast<short*>(&h);
  lo = *reinterpret_cast<short*>(&l);
}

__device__ __forceinline__ unsigned fkey(float f) {
  unsigned u = __float_as_uint(f);
  if ((u << 1) == 0u) u = 0u;             // canonicalize -0.0 -> +0.0
  return (u & 0x80000000u) ? ~u : (u | 0x80000000u);
}

__global__ void rope_tab_k(float* __restrict__ ct, float* __restrict__ st) {
  int idx = blockIdx.x * blockDim.x + threadIdx.x;
  if (idx >= SS * 32) return;
  int s = idx >> 5, j = idx & 31;
  float theta = 1.0f / powf(10000.0f, (float)(2 * j) / 64.0f);
  float ang = (float)s * theta;
  float sv, cv;
  sincosf(ang, &sv, &cv);
  ct[idx] = cv;
  st[idx] = sv;
}

// X[M][1024] fp32 -> A[M][3072] bf16 triplets (hi,hi,lo)
__global__ __launch_bounds__(256) void pack_a_k(
    const float* __restrict__ X, short* __restrict__ A, int total4)
{
  int idx = blockIdx.x * 256 + threadIdx.x;
  if (idx >= total4) return;
  float4 v = ((const float4*)X)[idx];
  float a4[4] = {v.x, v.y, v.z, v.w};
  short o[12];
#pragma unroll
  for (int j = 0; j < 4; ++j) {
    short hs, ls; split_bf16(a4[j], hs, ls);
    o[3*j] = hs; o[3*j+1] = hs; o[3*j+2] = ls;
  }
  short* op = A + (size_t)idx * 12;
  *(short4*)(op)     = *(short4*)&o[0];
  *(short4*)(op + 4) = *(short4*)&o[4];
  *(short4*)(op + 8) = *(short4*)&o[8];
}

// W[K=1024][Nw] fp32 -> BT rows [n][3072] bf16 triplets (hi,lo,hi)
__global__ __launch_bounds__(256) void pack_bt_k(
    const float* __restrict__ W, short* __restrict__ BT, int Nw)
{
  __shared__ float tile[32][33];
  int kb = blockIdx.y * 32, nb = blockIdx.x * 32;
  int tx = threadIdx.x & 31, ty = threadIdx.x >> 5;
  for (int yy = ty; yy < 32; yy += 8) {
    float v = 0.f;
    if (nb + tx < Nw) v = W[(size_t)(kb + yy) * Nw + nb + tx];
    tile[yy][tx] = v;
  }
  __syncthreads();
  for (int yy = ty; yy < 32; yy += 8) {
    int n = nb + yy;
    if (n >= Nw) continue;
    int k = kb + tx;
    float f = tile[tx][yy];
    short hs, ls; split_bf16(f, hs, ls);
    short* orow = BT + (size_t)n * KP + 3 * k;
    orow[0] = hs; orow[1] = ls; orow[2] = hs;
  }
}

// Wcat[k][0:256]=Wq, [256:320]=Wk, [320:324]=Ww
__global__ __launch_bounds__(256) void pack_wcat_k(
    const float* __restrict__ Wq, const float* __restrict__ Wk,
    const float* __restrict__ Ww, float* __restrict__ Wcat)
{
  int idx = blockIdx.x * 256 + threadIdx.x;
  if (idx >= 1024 * NCAT) return;
  int k = idx / NCAT, n = idx - k * NCAT;
  float v;
  if (n < 256)      v = Wq[(size_t)k * 256 + n];
  else if (n < 320) v = Wk[(size_t)k * 64 + (n - 256)];
  else              v = Ww[(size_t)k * 4 + (n - 320)];
  Wcat[idx] = v;
}

// bf16 MFMA GEMM: C[M][N] = A[M][Kp]*BT[N][Kp]^T. 128x128, BK=64, 4 waves,
// global_load_lds (width=16) staging.
__global__ __launch_bounds__(256) void gemm_bf16(
    const short* __restrict__ A, const short* __restrict__ BT,
    float* __restrict__ C, int M, int N, int Kp)
{
  __shared__ short As[128 * 64];
  __shared__ short Bs[128 * 64];
  const int tid = threadIdx.x;
  const int lane = tid & 63;
  const int wv = tid >> 6;
  const int m0 = blockIdx.y * 128, n0 = blockIdx.x * 128;
  const int wr = (wv >> 1) * 64, wc = (wv & 1) * 64;
  f32x4 acc[4][4];
#pragma unroll
  for (int i = 0; i < 4; ++i)
#pragma unroll
    for (int j = 0; j < 4; ++j)
#pragma unroll
      for (int r = 0; r < 4; ++r) acc[i][j][r] = 0.0f;

  const int rsel = lane & 15;
  const int lrow = lane >> 3;          // 0..7
  const int lcol = (lane & 7) * 8;     // shorts
  for (int k0 = 0; k0 < Kp; k0 += 64) {
#pragma unroll
    for (int q = 0; q < 4; ++q) {
      int c = wv * 4 + q;              // chunk 0..15 (8 rows each)
      int row = c * 8 + lrow;
      gload16(A  + (size_t)(m0 + row) * Kp + k0 + lcol, &As[c * 512]);
      gload16(BT + (size_t)(n0 + row) * Kp + k0 + lcol, &Bs[c * 512]);
    }
    __syncthreads();
#pragma unroll
    for (int kk = 0; kk < 2; ++kk) {
      bf16x8 af[4], bfr[4];
      int kof = kk * 32 + (lane >> 4) * 8;
#pragma unroll
      for (int i = 0; i < 4; ++i) {
        af[i]  = *(const bf16x8*)&As[(wr + i * 16 + rsel) * 64 + kof];
        bfr[i] = *(const bf16x8*)&Bs[(wc + i * 16 + rsel) * 64 + kof];
      }
#pragma unroll
      for (int i = 0; i < 4; ++i)
#pragma unroll
        for (int j = 0; j < 4; ++j)
          acc[i][j] = __builtin_amdgcn_mfma_f32_16x16x32_bf16(af[i], bfr[j], acc[i][j], 0, 0, 0);
    }
    __syncthreads();
  }
  const int er = m0 + wr + (lane >> 4) * 4;
  const int ec = n0 + wc + rsel;
#pragma unroll
  for (int i = 0; i < 4; ++i)
#pragma unroll
    for (int j = 0; j < 4; ++j)
#pragma unroll
      for (int r = 0; r < 4; ++r)
        C[(size_t)(er + i * 16 + r) * N + ec + j * 16] = acc[i][j][r];
}

// fp32 GEMM for the precision-critical indexer projections, 128x128, BK=16.
template<bool BND>
__global__ __launch_bounds__(256) void gemm128f(
    const float* __restrict__ A, const float* __restrict__ Bw, float* __restrict__ C,
    int M, int N, int K)
{
  __shared__ float As[16][132];
  __shared__ float Bs[16][132];
  int n0 = blockIdx.x * 128, m0 = blockIdx.y * 128;
  int tid = threadIdx.x;
  int tm = (tid >> 4) << 3;
  int tn = (tid & 15) << 3;
  float acc[8][8];
#pragma unroll
  for (int i = 0; i < 8; ++i)
#pragma unroll
    for (int j = 0; j < 8; ++j) acc[i][j] = 0.0f;

  for (int k0 = 0; k0 < K; k0 += 16) {
#pragma unroll
    for (int q = 0; q < 2; ++q) {
      int lin = tid * 4 + q * 1024;
      int row = lin >> 4, kk = lin & 15;
      float4 av = *(const float4*)(A + (size_t)(m0 + row) * K + k0 + kk);
      As[kk + 0][row] = av.x; As[kk + 1][row] = av.y;
      As[kk + 2][row] = av.z; As[kk + 3][row] = av.w;
      int bk = lin >> 7, bc = lin & 127;
      float4 bv;
      if (!BND || (n0 + bc) < N)
        bv = *(const float4*)(Bw + (size_t)(k0 + bk) * N + n0 + bc);
      else
        bv = make_float4(0.f, 0.f, 0.f, 0.f);
      *(float4*)&Bs[bk][bc] = bv;
    }
    __syncthreads();
#pragma unroll
    for (int k = 0; k < 16; ++k) {
      float a[8], bb[8];
      *(float4*)&a[0]  = *(const float4*)&As[k][tm];
      *(float4*)&a[4]  = *(const float4*)&As[k][tm + 4];
      *(float4*)&bb[0] = *(const float4*)&Bs[k][tn];
      *(float4*)&bb[4] = *(const float4*)&Bs[k][tn + 4];
#pragma unroll
      for (int i = 0; i < 8; ++i)
#pragma unroll
        for (int j = 0; j < 8; ++j)
          acc[i][j] = fmaf(a[i], bb[j], acc[i][j]);
    }
    __syncthreads();
  }
#pragma unroll
  for (int i = 0; i < 8; ++i) {
    size_t m = (size_t)(m0 + tm + i);
    float* crow = C + m * (size_t)N;
#pragma unroll
    for (int jc = 0; jc < 2; ++jc) {
      int cb = n0 + tn + jc * 4;
      if (!BND || cb < N) {
        *(float4*)(crow + cb) = make_float4(acc[i][jc*4], acc[i][jc*4+1],
                                            acc[i][jc*4+2], acc[i][jc*4+3]);
      }
    }
  }
}

// C[M][3072] -> RoPE(q,k) + fp16 cast; Qh/Kh/Vh all fp16
__global__ __launch_bounds__(256) void qkv_post_k(
    const float* __restrict__ C, const float* __restrict__ ct, const float* __restrict__ st,
    __half* __restrict__ Qh, __half* __restrict__ Kh, __half* __restrict__ Vh)
{
  int idx = blockIdx.x * 256 + threadIdx.x;
  if (idx >= ROWS * 384) return;
  int m = idx / 384;
  int g = idx - m * 384;
  int col0 = g * 8;
  const float* cp = C + (size_t)m * 3072 + col0;
  float4 v0 = *(const float4*)cp;
  float4 v1 = *(const float4*)(cp + 4);
  float a[8] = {v0.x, v0.y, v0.z, v0.w, v1.x, v1.y, v1.z, v1.w};
  int sec = col0 >> 10;
  int cin = col0 & 1023;
  size_t orow = (size_t)m * 1024 + cin;
  if (sec == 2) {
    __half2 hh[4];
#pragma unroll
    for (int c = 0; c < 4; ++c) hh[c] = __floats2half2_rn(a[2*c], a[2*c+1]);
    *(float4*)(Vh + orow) = *(float4*)hh;
  } else {
    int t = m & (SS - 1);
    int jb = (cin & 63) >> 1;
    float o[8];
#pragma unroll
    for (int c = 0; c < 4; ++c) {
      float cv = ct[t * 32 + jb + c], sv = st[t * 32 + jb + c];
      float x1 = a[2*c], x2 = a[2*c+1];
      o[2*c]   = x1 * cv - x2 * sv;
      o[2*c+1] = x2 * cv + x1 * sv;
    }
    __half2 hh[4];
#pragma unroll
    for (int c = 0; c < 4; ++c) hh[c] = __floats2half2_rn(o[2*c], o[2*c+1]);
    __half* dst = (sec == 0) ? Qh : Kh;
    *(float4*)(dst + orow) = *(float4*)hh;
  }
}

// Per (b,t): indexer scores for s<=t from Ccat (stride NCAT), exact top-512.
__global__ __launch_bounds__(256) void idx_topk_k(
    const float* __restrict__ Ccat, int* __restrict__ sel)
{
  int t = blockIdx.x, b = blockIdx.y;
  int tid = threadIdx.x;
  int* srow = sel + ((size_t)b * SS + t) * TOPK;
  if (t < TOPK) {  // -1e9 ties => selection is exactly [0..511]
    for (int i = tid; i < TOPK; i += 256) srow[i] = i;
    return;
  }
  __shared__ float sc[SS];
  __shared__ unsigned hist[256];
  __shared__ unsigned hs[256];
  __shared__ unsigned s_bsel, s_above, s_cnt;

  const float4* qrow = (const float4*)(Ccat + ((size_t)b * SS + t) * NCAT);
  const float* wrow = Ccat + ((size_t)b * SS + t) * NCAT + 320;
  float w0 = wrow[0], w1 = wrow[1], w2 = wrow[2], w3 = wrow[3];

  for (int s = tid; s <= t; s += 256) {
    const float4* kp = (const float4*)(Ccat + ((size_t)b * SS + s) * NCAT + 256);
    float a0 = 0.f, a1 = 0.f, a2 = 0.f, a3 = 0.f;
#pragma unroll
    for (int d4 = 0; d4 < 16; ++d4) {
      float4 kv = kp[d4];
      float4 q0 = qrow[d4];
      float4 q1 = qrow[16 + d4];
      float4 q2 = qrow[32 + d4];
      float4 q3 = qrow[48 + d4];
      a0 += q0.x * kv.x + q0.y * kv.y + q0.z * kv.z + q0.w * kv.w;
      a1 += q1.x * kv.x + q1.y * kv.y + q1.z * kv.z + q1.w * kv.w;
      a2 += q2.x * kv.x + q2.y * kv.y + q2.z * kv.z + q2.w * kv.w;
      a3 += q3.x * kv.x + q3.y * kv.y + q3.z * kv.z + q3.w * kv.w;
    }
    float v = fmaxf(a0, 0.f) * w0 + fmaxf(a1, 0.f) * w1 +
              fmaxf(a2, 0.f) * w2 + fmaxf(a3, 0.f) * w3;
    sc[s] = v;
  }
  __syncthreads();

  unsigned krem = TOPK;
  unsigned prefix = 0;
#pragma unroll 1
  for (int p = 0; p < 4; ++p) {
    int shift = 24 - 8 * p;
    unsigned maskAbove = (p == 0) ? 0u : (0xFFFFFFFFu << (shift + 8));
    hist[tid] = 0u;
    __syncthreads();
    for (int s = tid; s <= t; s += 256) {
      unsigned key = fkey(sc[s]);
      if ((key & maskAbove) == prefix)
        atomicAdd(&hist[(key >> shift) & 255], 1u);
    }
    __syncthreads();
    hs[tid] = hist[tid];
    __syncthreads();
#pragma unroll 1
    for (int off = 1; off < 256; off <<= 1) {
      unsigned v = (tid + off < 256) ? hs[tid + off] : 0u;
      __syncthreads();
      hs[tid] += v;
      __syncthreads();
    }
    unsigned mine = hs[tid];
    unsigned nxt = (tid < 255) ? hs[tid + 1] : 0u;
    if (mine >= krem && nxt < krem) { s_bsel = (unsigned)tid; s_above = nxt; }
    __syncthreads();
    prefix |= (s_bsel << shift);
    krem -= s_above;
    __syncthreads();
  }

  unsigned Tkey = prefix;
  unsigned kfin = krem;
  if (tid == 0) s_cnt = 0u;
  __syncthreads();
  for (int s = tid; s <= t; s += 256) {
    if (fkey(sc[s]) > Tkey) {
      unsigned pp = atomicAdd(&s_cnt, 1u);
      srow[pp] = s;
    }
  }
  __syncthreads();
  unsigned cgt = s_cnt;
  if (tid < 64) {
    unsigned taken = 0;
    for (int s0 = 0; s0 <= t && taken < kfin; s0 += 64) {
      int s = s0 + tid;
      bool pred = (s <= t) && (fkey(sc[s]) == Tkey);
      unsigned long long mba = __ballot(pred);
      unsigned pre = (unsigned)__popcll(mba & ((1ull << tid) - 1ull));
      if (pred && (taken + pre) < kfin) srow[cgt + taken + pre] = s;
      taken += (unsigned)__popcll(mba);
    }
  }
}

// Gather attention, latency-optimized: 4-key groups, explicit double-buffered
// prefetch in both QK and PV phases. Q/K/V fp16; dot2 math.
#define LK(buf, g0) { \
  _Pragma("unroll") \
  for (int u_ = 0; u_ < 4; ++u_) { \
    int s_ = sidx[base + (((g0) + u_) & 127)]; \
    const float4* p_ = (const float4*)(Kh + (brow + s_) * 1024 + lane * 16); \
    *(float4*)&buf[u_][0] = p_[0]; \
    *(float4*)&buf[u_][4] = p_[1]; \
  } }

#define CK(buf, g0) { \
  float d_[4]; \
  _Pragma("unroll") \
  for (int u_ = 0; u_ < 4; ++u_) { \
    float dd_ = 0.f; \
    _Pragma("unroll") \
    for (int w_ = 0; w_ < 8; ++w_) dd_ = fdot2(qq[w_], buf[u_][w_], dd_); \
    d_[u_] = dd_; \
  } \
  _Pragma("unroll") \
  for (int u_ = 0; u_ < 4; ++u_) { \
    d_[u_] += __shfl_xor(d_[u_], 1); \
    d_[u_] += __shfl_xor(d_[u_], 2); \
  } \
  if ((lane & 3) == 0) { \
    _Pragma("unroll") \
    for (int u_ = 0; u_ < 4; ++u_) P[base + (g0) + u_][h4] = d_[u_] * 0.125f; \
  } }

#define LV(buf, j0) { \
  _Pragma("unroll") \
  for (int u_ = 0; u_ < 4; ++u_) { \
    int jj_ = ((j0) + u_) & 255; \
    int2 ss_ = *(const int2*)&sidx[2 * jj_]; \
    float2 va_ = *(const float2*)(vb + (size_t)ss_.x * 1024); \
    float2 vw_ = *(const float2*)(vb + (size_t)ss_.y * 1024); \
    buf[u_][0] = __float_as_uint(va_.x); buf[u_][1] = __float_as_uint(va_.y); \
    buf[u_][2] = __float_as_uint(vw_.x); buf[u_][3] = __float_as_uint(vw_.y); \
  } }

#define CV(buf, j0) { \
  _Pragma("unroll") \
  for (int u_ = 0; u_ < 4; ++u_) { \
    int jj_ = (j0) + u_; \
    u32 pv_ = Ph2u[jj_ * 17 + h]; \
    a0 = fdot2(pv_, __builtin_amdgcn_perm(buf[u_][0], buf[u_][2], 0x01000504u), a0); \
    a1 = fdot2(pv_, __builtin_amdgcn_perm(buf[u_][0], buf[u_][2], 0x03020706u), a1); \
    a2 = fdot2(pv_, __builtin_amdgcn_perm(buf[u_][1], buf[u_][3], 0x01000504u), a2); \
    a3 = fdot2(pv_, __builtin_amdgcn_perm(buf[u_][1], buf[u_][3], 0x03020706u), a3); \
  } }

__global__ __launch_bounds__(256) void attn_k(
    const __half* __restrict__ Qh, const __half* __restrict__ Kh, const __half* __restrict__ Vh,
    const int* __restrict__ sel, float* __restrict__ attnO)
{
  int bid = blockIdx.x;
  int xcd = bid & 7, jg = bid >> 3;
  int b = xcd >> 2;
  int t = (xcd & 3) * 512 + jg;
  int tid = threadIdx.x;
  int lane = tid & 63;
  int wv = tid >> 6;
  __shared__ float P[TOPK][17];
  __shared__ int sidx[TOPK];
  __shared__ float denomS[16];

  if (t < TOPK) {
    for (int i = tid; i < TOPK; i += 256) sidx[i] = i;
  } else {
    const int* srow = sel + ((size_t)b * SS + t) * TOPK;
    for (int i = tid; i < TOPK; i += 256) sidx[i] = srow[i];
  }
  const size_t brow = (size_t)b * SS;
  const __half* qrow = Qh + (brow + t) * 1024 + lane * 16;
  u32 qq[8];
  *(float4*)&qq[0] = *(const float4*)(qrow);
  *(float4*)&qq[4] = *(const float4*)(qrow + 8);
  __syncthreads();

  int h4 = lane >> 2;
  // QK: 128 keys per wave, 4-key groups, double-buffered prefetch
  {
    int base = wv * 128;
    u32 kA[4][8], kB[4][8];
    LK(kA, 0);
#pragma unroll 1
    for (int g = 0; g < 128; g += 8) {
      LK(kB, g + 4);
      CK(kA, g);
      LK(kA, (g + 8) & 127);
      CK(kB, g + 4);
    }
  }
  __syncthreads();

  int h = tid >> 4, i0 = tid & 15;
  float mx = -3.0e38f;
  for (int i = i0; i < TOPK; i += 16) mx = fmaxf(mx, P[i][h]);
#pragma unroll
  for (int off = 1; off < 16; off <<= 1) mx = fmaxf(mx, __shfl_xor(mx, off));
  float sum = 0.f;
  u32 pk[16];
#pragma unroll
  for (int jj = 0; jj < 16; ++jj) {
    int i2 = i0 + 16 * jj;
    float e0 = __expf(P[2 * i2][h] - mx);
    float e1 = __expf(P[2 * i2 + 1][h] - mx);
    sum += e0 + e1;
    pk[jj] = pkh2(e0, e1);
  }
#pragma unroll
  for (int off = 1; off < 16; off <<= 1) sum += __shfl_xor(sum, off);
  if (i0 == 0) denomS[h] = sum;
  __syncthreads();                       // all raw-P reads done
  u32* Ph2u = (u32*)&P[0][0];            // reuse P storage: [256][17] half2 rows
#pragma unroll
  for (int jj = 0; jj < 16; ++jj) Ph2u[(i0 + 16 * jj) * 17 + h] = pk[jj];
  __syncthreads();

  // PV: 256 key-pairs, 4-pair groups, double-buffered prefetch
  int dq = (tid & 15) << 2;
  size_t hoff = (size_t)h * 64 + dq;
  const __half* vb = Vh + brow * 1024 + hoff;
  float a0 = 0.f, a1 = 0.f, a2 = 0.f, a3 = 0.f;
  {
    u32 vA[4][4], vB[4][4];
    LV(vA, 0);
#pragma unroll 1
    for (int j = 0; j < 256; j += 8) {
      LV(vB, j + 4);
      CV(vA, j);
      LV(vA, (j + 8) & 255);
      CV(vB, j + 4);
    }
  }
  float inv = 1.0f / denomS[h];
  *(float4*)(attnO + (brow + t) * 1024 + hoff) =
      make_float4(a0 * inv, a1 * inv, a2 * inv, a3 * inv);
}

extern "C" void kernel_launch(void* const* d_in, const int* in_sizes, int n_in,
                              void* d_out, int out_size, void* d_ws, size_t ws_size,
                              hipStream_t stream) {
  const float* x    = (const float*)d_in[0];
  const float* Wqkv = (const float*)d_in[1];
  const float* Wo   = (const float*)d_in[2];
  const float* Wq   = (const float*)d_in[3];
  const float* Wk   = (const float*)d_in[4];
  const float* Ww   = (const float*)d_in[5];
  float* out = (float*)d_out;

  float* fws = (float*)d_ws;
  size_t o = 0;
  __half* Qh    = (__half*)(fws + o);  o += (size_t)ROWS * 512;
  __half* Kh    = (__half*)(fws + o);  o += (size_t)ROWS * 512;
  __half* Vh    = (__half*)(fws + o);  o += (size_t)ROWS * 512;
  int*    sel   = (int*)(fws + o);     o += (size_t)ROWS * TOPK;
  float*  ct    = fws + o;             o += (size_t)SS * 32;
  float*  st    = fws + o;             o += (size_t)SS * 32;
  float*  Ccat  = fws + o;             o += (size_t)ROWS * NCAT;       // fused qi|ki|w
  short*  BTwo  = (short*)(fws + o);   o += (size_t)1024 * KP / 2;
  short*  BTq   = (short*)(fws + o);   o += (size_t)3072 * KP / 2;
  short*  Ax    = (short*)(fws + o);                                   // aliased region (ROWS*KP shorts):
  float*  attnO = fws + o;                                             //  attnO reuses Ax after qkv gemm
  float*  Wcat  = fws + o + (size_t)ROWS * 1024;                       //  Wcat in tail (after attnO's span; Ax dead by then)
  /* region size */                    o += (size_t)ROWS * KP / 2;
  float*  Cbuf  = fws + o;                                             // aliased region:
  short*  Aattn = (short*)(fws + o);   o += (size_t)ROWS * 3072;       //  Aattn reuses Cbuf

  rope_tab_k<<<dim3((SS * 32 + 255) / 256), dim3(256), 0, stream>>>(ct, st);

  // packs for the two MFMA GEMMs
  pack_a_k<<<dim3(ROWS * KDIM / 4 / 256), dim3(256), 0, stream>>>(x, Ax, ROWS * KDIM / 4);
  pack_bt_k<<<dim3(3072 / 32, 32), dim3(256), 0, stream>>>(Wqkv, BTq, 3072);
  pack_bt_k<<<dim3(1024 / 32, 32), dim3(256), 0, stream>>>(Wo, BTwo, 1024);

  // qkv GEMM (split-bf16 MFMA): Cbuf[4096][3072] = x * Wqkv   (last use of Ax)
  gemm_bf16<<<dim3(3072 / 128, ROWS / 128), dim3(256), 0, stream>>>(
      Ax, BTq, Cbuf, ROWS, 3072, KP);
  qkv_post_k<<<dim3((ROWS * 384 + 255) / 256), dim3(256), 0, stream>>>(Cbuf, ct, st, Qh, Kh, Vh);

  // fused indexer projections in fp32 (bit-identical math to the split version)
  pack_wcat_k<<<dim3((1024 * NCAT + 255) / 256), dim3(256), 0, stream>>>(Wq, Wk, Ww, Wcat);
  gemm128f<true><<<dim3(3, ROWS / 128), dim3(256), 0, stream>>>(x, Wcat, Ccat, ROWS, NCAT, 1024);

  idx_topk_k<<<dim3(SS, BB), dim3(256), 0, stream>>>(Ccat, sel);
  attn_k<<<dim3(ROWS), dim3(256), 0, stream>>>(Qh, Kh, Vh, sel, attnO);

  // out = attn @ Wo (split-bf16 MFMA)
  pack_a_k<<<dim3(ROWS * KDIM / 4 / 256), dim3(256), 0, stream>>>(attnO, Aattn, ROWS * KDIM / 4);
  gemm_bf16<<<dim3(1024 / 128, ROWS / 128), dim3(256), 0, stream>>>(
      Aattn, BTwo, out, ROWS, 1024, KP);
}